// Round 1
// baseline (1462.071 us; speedup 1.0000x reference)
//
#include <hip/hip_runtime.h>
#include <math.h>

// ---------------------------------------------------------------------------
// EmbedMatcher: V=200000 D=256 B=2048 F=5 N=64 K=32 DM=512 HID=1024 STEPS=4
// Key algebraic simplifications (verified against reference):
//  * GCN: tanh(mean_k(cat) @ W + b)  == tanh((cat@W).mean_k + b)   (linear)
//  * attn = softmax over a single column -> all ones -> r == support_g const
//  * gates = base + h @ Whh[:, :512]^T + cvec,  base/cvec step-invariant
//  * step 0: h_r = 0 -> gates == base
// ---------------------------------------------------------------------------

__device__ inline float wave_reduce_sum(float v) {
#pragma unroll
  for (int off = 32; off > 0; off >>= 1) v += __shfl_down(v, off, 64);
  return v;
}

// ---------------- neighbor encoder: one block (256 thr) per row ------------
__global__ __launch_bounds__(256) void neighbor_kernel(
    const int* __restrict__ query, const int* __restrict__ support,
    const int* __restrict__ qlc, const int* __restrict__ qrc,
    const int* __restrict__ slc, const int* __restrict__ src_,
    const float* __restrict__ emb, float* __restrict__ mc, int B, int F) {
  const int r = blockIdx.x;
  const int tid = threadIdx.x;
  const int* conn;
  int id;
  if (r < B) {
    conn = qlc + (size_t)r * 128; id = query[2 * r];
  } else if (r < 2 * B) {
    int b = r - B; conn = qrc + (size_t)b * 128; id = query[2 * b + 1];
  } else if (r < 2 * B + F) {
    int f = r - 2 * B; conn = slc + (size_t)f * 128; id = support[2 * f];
  } else {
    int f = r - 2 * B - F; conn = src_ + (size_t)f * 128; id = support[2 * f + 1];
  }

  __shared__ __align__(16) float cent[256];
  __shared__ float sims[64];
  __shared__ int rel_ids[64];
  __shared__ int ent_ids[64];
  __shared__ unsigned char sel[64];
  __shared__ float red[4];
  __shared__ float cnorm_s;

  if (tid < 64) {
    rel_ids[tid] = conn[2 * tid];
    ent_ids[tid] = conn[2 * tid + 1];
  }
  float cv = emb[(size_t)id * 256 + tid];
  cent[tid] = cv;
  float sq = wave_reduce_sum(cv * cv);
  if ((tid & 63) == 0) red[tid >> 6] = sq;
  __syncthreads();
  if (tid == 0) cnorm_s = sqrtf(red[0] + red[1] + red[2] + red[3]);
  __syncthreads();
  const float cn = cnorm_s;

  const int wave = tid >> 6, lane = tid & 63;
  const float4 cv4 = *(const float4*)(cent + lane * 4);
  for (int n = wave; n < 64; n += 4) {
    const float* er = emb + (size_t)ent_ids[n] * 256;
    float4 e = *(const float4*)(er + lane * 4);
    float d = e.x * cv4.x + e.y * cv4.y + e.z * cv4.z + e.w * cv4.w;
    float s2 = e.x * e.x + e.y * e.y + e.z * e.z + e.w * e.w;
#pragma unroll
    for (int off = 32; off > 0; off >>= 1) {
      d += __shfl_down(d, off, 64);
      s2 += __shfl_down(s2, off, 64);
    }
    if (lane == 0) sims[n] = d / fmaxf(cn * sqrtf(s2), 1e-8f);
  }
  __syncthreads();

  // top-K=32 with stable (lower-index-first) tie-break, matching lax.top_k
  if (tid < 64) {
    float my = sims[tid];
    int rank = 0;
#pragma unroll 8
    for (int j = 0; j < 64; ++j) {
      float sj = sims[j];
      rank += (sj > my) || (sj == my && j < tid);
    }
    sel[tid] = (rank < 32) ? 1 : 0;
  }
  __syncthreads();

  float accR = 0.f, accE = 0.f;
  for (int n = 0; n < 64; ++n) {
    if (sel[n]) {
      accR += emb[(size_t)rel_ids[n] * 256 + tid];
      accE += emb[(size_t)ent_ids[n] * 256 + tid];
    }
  }
  mc[(size_t)r * 512 + tid] = accR * (1.f / 32.f);
  mc[(size_t)r * 512 + 256 + tid] = accE * (1.f / 32.f);
}

// ------------- generic fp32 GEMM_NT: C[i,j] = sum_k A[i,k]*B[j,k] ----------
// N must be a multiple of 64, K a multiple of 16. M arbitrary.
// epilogue: v = acc (+bias1[j]) (+bias2[j]) (+addmat[i,j]); act 0=none 1=tanh 2=relu
__global__ __launch_bounds__(256) void gemm_nt_kernel(
    const float* __restrict__ A, int lda, const float* __restrict__ B, int ldb,
    float* __restrict__ C, int M, int N, int K,
    const float* __restrict__ bias1, const float* __restrict__ bias2,
    const float* __restrict__ addmat, int act) {
  __shared__ float As[16][65];
  __shared__ float Bs[16][65];
  const int tid = threadIdx.x;
  const int col0 = blockIdx.x * 64;
  const int row0 = blockIdx.y * 64;
  const int tx = tid & 15, ty = tid >> 4;
  const int lr = tid >> 2, lk = (tid & 3) << 2;

  float acc[4][4];
#pragma unroll
  for (int i = 0; i < 4; ++i)
#pragma unroll
    for (int j = 0; j < 4; ++j) acc[i][j] = 0.f;

  const int ar = row0 + lr;
  const bool avalid = ar < M;
  const float* Aptr = A + (size_t)ar * lda + lk;
  const float* Bptr = B + (size_t)(col0 + lr) * ldb + lk;

  for (int k0 = 0; k0 < K; k0 += 16) {
    float4 av = make_float4(0.f, 0.f, 0.f, 0.f);
    if (avalid) av = *(const float4*)(Aptr + k0);
    float4 bv = *(const float4*)(Bptr + k0);
    As[lk + 0][lr] = av.x; As[lk + 1][lr] = av.y;
    As[lk + 2][lr] = av.z; As[lk + 3][lr] = av.w;
    Bs[lk + 0][lr] = bv.x; Bs[lk + 1][lr] = bv.y;
    Bs[lk + 2][lr] = bv.z; Bs[lk + 3][lr] = bv.w;
    __syncthreads();
#pragma unroll
    for (int k = 0; k < 16; ++k) {
      float a0 = As[k][ty * 4 + 0], a1 = As[k][ty * 4 + 1];
      float a2 = As[k][ty * 4 + 2], a3 = As[k][ty * 4 + 3];
      float b0 = Bs[k][tx * 4 + 0], b1 = Bs[k][tx * 4 + 1];
      float b2 = Bs[k][tx * 4 + 2], b3 = Bs[k][tx * 4 + 3];
      acc[0][0] += a0 * b0; acc[0][1] += a0 * b1; acc[0][2] += a0 * b2; acc[0][3] += a0 * b3;
      acc[1][0] += a1 * b0; acc[1][1] += a1 * b1; acc[1][2] += a1 * b2; acc[1][3] += a1 * b3;
      acc[2][0] += a2 * b0; acc[2][1] += a2 * b1; acc[2][2] += a2 * b2; acc[2][3] += a2 * b3;
      acc[3][0] += a3 * b0; acc[3][1] += a3 * b1; acc[3][2] += a3 * b2; acc[3][3] += a3 * b3;
    }
    __syncthreads();
  }

#pragma unroll
  for (int i = 0; i < 4; ++i) {
    const int r = row0 + ty * 4 + i;
    if (r >= M) continue;
#pragma unroll
    for (int j = 0; j < 4; ++j) {
      const int c = col0 + tx * 4 + j;
      float v = acc[i][j];
      if (bias1) v += bias1[c];
      if (bias2) v += bias2[c];
      if (addmat) v += addmat[(size_t)r * N + c];
      if (act == 1) v = tanhf(v);
      else if (act == 2) v = fmaxf(v, 0.f);
      C[(size_t)r * N + c] = v;
    }
  }
}

// ------------- remap enc (NR x 256) -> qn (B x 512), sn (F x 512) ----------
__global__ __launch_bounds__(256) void remap_kernel(
    const float* __restrict__ enc, float* __restrict__ qn,
    float* __restrict__ sn, int B, int F) {
  const int idx = blockIdx.x * 256 + threadIdx.x;
  const int i = idx >> 8, d = idx & 255;
  const float v = enc[idx];
  if (i < B) qn[(size_t)i * 512 + d] = v;
  else if (i < 2 * B) qn[(size_t)(i - B) * 512 + 256 + d] = v;
  else if (i < 2 * B + F) sn[(size_t)(i - 2 * B) * 512 + d] = v;
  else sn[(size_t)(i - 2 * B - F) * 512 + 256 + d] = v;
}

// ------------- LayerNorm over rows of length 512 ---------------------------
__global__ __launch_bounds__(256) void ln_kernel(
    const float* __restrict__ X, float* __restrict__ Y,
    const float* __restrict__ g, const float* __restrict__ bta) {
  const int r = blockIdx.x;
  const int tid = threadIdx.x;
  const float* x = X + (size_t)r * 512;
  float x0 = x[tid], x1 = x[tid + 256];
  __shared__ float red[4];
  float s = wave_reduce_sum(x0 + x1);
  if ((tid & 63) == 0) red[tid >> 6] = s;
  __syncthreads();
  const float mean = (red[0] + red[1] + red[2] + red[3]) * (1.f / 512.f);
  __syncthreads();
  const float d0 = x0 - mean, d1 = x1 - mean;
  float v = wave_reduce_sum(d0 * d0 + d1 * d1);
  if ((tid & 63) == 0) red[tid >> 6] = v;
  __syncthreads();
  const float var = (red[0] + red[1] + red[2] + red[3]) * (1.f / 512.f);
  const float inv = 1.f / sqrtf(var + 1e-5f);
  float* y = Y + (size_t)r * 512;
  y[tid] = d0 * inv * g[tid] + bta[tid];
  y[tid + 256] = d1 * inv * g[tid + 256] + bta[tid + 256];
}

// ------------- mean over F support rows -> sg (512) ------------------------
__global__ void smean_kernel(const float* __restrict__ ss,
                             float* __restrict__ sg, int F) {
  const int d = blockIdx.x * blockDim.x + threadIdx.x;
  if (d < 512) {
    float s = 0.f;
    for (int f = 0; f < F; ++f) s += ss[(size_t)f * 512 + d];
    sg[d] = s / (float)F;
  }
}

// ------------- cvec[j] = sum_d sg[d] * w_hh[j, 512+d], j < 4096 ------------
__global__ __launch_bounds__(256) void cvec_kernel(
    const float* __restrict__ whh, const float* __restrict__ sg,
    float* __restrict__ cv) {
  const int wave = threadIdx.x >> 6, lane = threadIdx.x & 63;
  const int j = blockIdx.x * 4 + wave;
  const float* wr = whh + (size_t)j * 1024 + 512;
  float s = 0.f;
#pragma unroll
  for (int d = lane; d < 512; d += 64) s += wr[d] * sg[d];
  s = wave_reduce_sum(s);
  if (lane == 0) cv[j] = s;
}

// ------------- LSTM cell elementwise ---------------------------------------
__global__ __launch_bounds__(256) void cell_kernel(
    const float* __restrict__ gates, float* __restrict__ c,
    const float* __restrict__ qg, float* __restrict__ h, int first) {
  const size_t idx = (size_t)blockIdx.x * 256 + threadIdx.x;
  const int b = (int)(idx >> 10), n = (int)(idx & 1023);
  const float* gr = gates + (size_t)b * 4096;
  const float gi = gr[n], gf = gr[1024 + n], gg = gr[2048 + n], go = gr[3072 + n];
  const float cold = first ? 0.f : c[idx];
  const float si = 1.f / (1.f + expf(-gi));
  const float sf = 1.f / (1.f + expf(-gf));
  const float cn = sf * cold + si * tanhf(gg);
  c[idx] = cn;
  if (n < 512) {
    const float so = 1.f / (1.f + expf(-go));
    h[(size_t)b * 512 + n] = qg[(size_t)b * 512 + n] + so * tanhf(cn);
  }
}

// ------------- out[b] = h[b].sg / (max(|h|,eps)*max(|sg|,eps)) -------------
__global__ __launch_bounds__(256) void final_kernel(
    const float* __restrict__ h, const float* __restrict__ sg,
    float* __restrict__ out) {
  const int b = blockIdx.x, tid = threadIdx.x;
  const float* hr = h + (size_t)b * 512;
  const float h0 = hr[tid], h1 = hr[tid + 256];
  const float s0 = sg[tid], s1 = sg[tid + 256];
  float d = h0 * s0 + h1 * s1;
  float hh = h0 * h0 + h1 * h1;
  float ssq = s0 * s0 + s1 * s1;
  __shared__ float red[3][4];
  d = wave_reduce_sum(d);
  hh = wave_reduce_sum(hh);
  ssq = wave_reduce_sum(ssq);
  if ((tid & 63) == 0) {
    red[0][tid >> 6] = d; red[1][tid >> 6] = hh; red[2][tid >> 6] = ssq;
  }
  __syncthreads();
  if (tid == 0) {
    const float D = red[0][0] + red[0][1] + red[0][2] + red[0][3];
    const float H = red[1][0] + red[1][1] + red[1][2] + red[1][3];
    const float S = red[2][0] + red[2][1] + red[2][2] + red[2][3];
    out[b] = D / (fmaxf(sqrtf(H), 1e-12f) * fmaxf(sqrtf(S), 1e-12f));
  }
}

extern "C" void kernel_launch(void* const* d_in, const int* in_sizes, int n_in,
                              void* d_out, int out_size, void* d_ws, size_t ws_size,
                              hipStream_t stream) {
  const int* query = (const int*)d_in[0];
  const int* support = (const int*)d_in[1];
  const int* qlc = (const int*)d_in[2];
  const int* qrc = (const int*)d_in[4];
  const int* slc = (const int*)d_in[6];
  const int* src_ = (const int*)d_in[8];
  const float* emb = (const float*)d_in[10];
  const float* gcn_w = (const float*)d_in[11];
  const float* gcn_wb = (const float*)d_in[12];
  const float* gcn_b = (const float*)d_in[13];
  const float* p1_w = (const float*)d_in[14];
  const float* p1_b = (const float*)d_in[15];
  const float* p2_w = (const float*)d_in[16];
  const float* p2_b = (const float*)d_in[17];
  const float* ln_g = (const float*)d_in[18];
  const float* ln_b = (const float*)d_in[19];
  const float* w_ih = (const float*)d_in[20];
  const float* w_hh = (const float*)d_in[21];
  const float* b_ih = (const float*)d_in[22];
  const float* b_hh = (const float*)d_in[23];
  float* out = (float*)d_out;

  const int B = in_sizes[0] / 2;   // 2048
  const int F = in_sizes[1] / 2;   // 5
  const int NR = 2 * B + 2 * F;    // 4106

  // ---- workspace layout (floats), time-disjoint aliasing -----------------
  float* W = (float*)d_ws;
  const size_t base_o = 0;                          // B*4096, L10..end
  const size_t gates_o = base_o + (size_t)B * 4096; // B*4096, steps 1..3
  const size_t mc_o = gates_o;                      // NR*512 (dead before gates)
  const size_t enc_o = mc_o + (size_t)NR * 512;     // NR*256 (dead before gates)
  const size_t hq_o = enc_o + (size_t)NR * 256;     // B*1024 (dead before gates)
  const size_t qn_o = gates_o + (size_t)B * 4096;   // B*512
  const size_t qg_o = qn_o + (size_t)B * 512;       // B*512
  const size_t cbuf_o = qg_o + (size_t)B * 512;     // B*1024
  const size_t oq_o = cbuf_o;                       // B*512 (dead before cbuf)
  const size_t hbuf_o = cbuf_o + (size_t)B * 1024;  // B*512
  const size_t sn_o = hbuf_o + (size_t)B * 512;     // F*512
  const size_t hs_o = sn_o + (size_t)F * 512;       // F*1024
  const size_t oss_o = hs_o + (size_t)F * 1024;     // F*512
  const size_t ssb_o = oss_o + (size_t)F * 512;     // F*512
  const size_t sg_o = ssb_o + (size_t)F * 512;      // 512
  const size_t cvec_o = sg_o + 512;                 // 4096
  // total ~= 22.04M floats ~= 88.2 MB

  auto gemm = [&](const float* A, int lda, const float* Bm, int ldb, float* C,
                  int M, int N, int K, const float* b1, const float* b2,
                  const float* add, int act) {
    dim3 g(N / 64, (M + 63) / 64);
    gemm_nt_kernel<<<g, 256, 0, stream>>>(A, lda, Bm, ldb, C, M, N, K, b1, b2,
                                          add, act);
  };

  // 1. neighbor encoder -> mc (NR x 512)
  neighbor_kernel<<<NR, 256, 0, stream>>>(query, support, qlc, qrc, slc, src_,
                                          emb, W + mc_o, B, F);
  // 2. GCN: enc = tanh(mc @ gcn_w^T + gcn_wb + gcn_b)   (NR x 256)
  gemm(W + mc_o, 512, gcn_w, 512, W + enc_o, NR, 256, 512, gcn_wb, gcn_b,
       nullptr, 1);
  // 3. remap -> qn (B x 512), sn (F x 512)
  remap_kernel<<<NR, 256, 0, stream>>>(W + enc_o, W + qn_o, W + sn_o, B, F);
  // 4-5. support_encoder(queries)
  gemm(W + qn_o, 512, p1_w, 512, W + hq_o, B, 1024, 512, p1_b, nullptr,
       nullptr, 2);
  gemm(W + hq_o, 1024, p2_w, 1024, W + oq_o, B, 512, 1024, p2_b, nullptr,
       W + qn_o, 0);
  // 6-7. support_encoder(supports)
  gemm(W + sn_o, 512, p1_w, 512, W + hs_o, F, 1024, 512, p1_b, nullptr,
       nullptr, 2);
  gemm(W + hs_o, 1024, p2_w, 1024, W + oss_o, F, 512, 1024, p2_b, nullptr,
       W + sn_o, 0);
  // 8. LN supports + mean -> sg
  ln_kernel<<<F, 256, 0, stream>>>(W + oss_o, W + ssb_o, ln_g, ln_b);
  smean_kernel<<<2, 256, 0, stream>>>(W + ssb_o, W + sg_o, F);
  // 9. LN queries -> qg
  ln_kernel<<<B, 256, 0, stream>>>(W + oq_o, W + qg_o, ln_g, ln_b);
  // 10. base = qg @ w_ih^T + b_ih + b_hh  (B x 4096)
  gemm(W + qg_o, 512, w_ih, 512, W + base_o, B, 4096, 512, b_ih, b_hh,
       nullptr, 0);
  // 11. cvec = sg @ w_hh[:,512:]^T  (4096)
  cvec_kernel<<<1024, 256, 0, stream>>>(w_hh, W + sg_o, W + cvec_o);
  // 12. LSTM step 0 (h_r = 0 -> gates == base)
  cell_kernel<<<(B * 1024) / 256, 256, 0, stream>>>(W + base_o, W + cbuf_o,
                                                    W + qg_o, W + hbuf_o, 1);
  // 13-16. steps 1..3
  for (int s = 1; s < 4; ++s) {
    gemm(W + hbuf_o, 512, w_hh, 1024, W + gates_o, B, 4096, 512, W + cvec_o,
         nullptr, W + base_o, 0);
    cell_kernel<<<(B * 1024) / 256, 256, 0, stream>>>(W + gates_o, W + cbuf_o,
                                                      W + qg_o, W + hbuf_o, 0);
  }
  // 17. output
  final_kernel<<<B, 256, 0, stream>>>(W + hbuf_o, W + sg_o, out);
}

// Round 2
// 901.322 us; speedup vs baseline: 1.6221x; 1.6221x over previous
//
#include <hip/hip_runtime.h>
#include <math.h>

// ---------------------------------------------------------------------------
// EmbedMatcher: V=200000 D=256 B=2048 F=5 N=64 K=32 DM=512 HID=1024 STEPS=4
// Algebraic simplifications (verified vs reference):
//  * GCN: tanh(mean_k(cat) @ W + b) == tanh(mean_k(cat) @ W + b)  (linear mean)
//  * attn = softmax over ONE column -> all ones -> r == support_g (constant)
//  * gates = base + h @ Whh[:, :512]^T + cvec;  base/cvec step-invariant
//  * step 0: h_r = 0 -> gates == base
// Round 1 -> 2: large GEMMs moved to bf16 MFMA (16x16x32), weights converted
// to bf16 per call, activations emit bf16 copies from producer kernels.
// ---------------------------------------------------------------------------

typedef __attribute__((ext_vector_type(8))) short short8;
typedef __attribute__((ext_vector_type(4))) float floatx4;

__device__ inline unsigned short f2bf(float f) {
  union { float f; unsigned int u; } x;
  x.f = f;
  unsigned int r = x.u + 0x7fffu + ((x.u >> 16) & 1u);  // RNE
  return (unsigned short)(r >> 16);
}

__device__ inline float wave_reduce_sum(float v) {
#pragma unroll
  for (int off = 32; off > 0; off >>= 1) v += __shfl_down(v, off, 64);
  return v;
}

// ---------------- fp32 -> bf16 convert (strided source) --------------------
__global__ __launch_bounds__(256) void convert_bf16_kernel(
    const float* __restrict__ in, int ld, int cols,
    unsigned short* __restrict__ out, int total) {
  const int idx = blockIdx.x * 256 + threadIdx.x;
  if (idx < total) {
    const int r = idx / cols, c = idx - r * cols;
    out[idx] = f2bf(in[(size_t)r * ld + c]);
  }
}

// ---------------- neighbor encoder: one block (256 thr) per row ------------
__global__ __launch_bounds__(256) void neighbor_kernel(
    const int* __restrict__ query, const int* __restrict__ support,
    const int* __restrict__ qlc, const int* __restrict__ qrc,
    const int* __restrict__ slc, const int* __restrict__ src_,
    const float* __restrict__ emb, unsigned short* __restrict__ mc,
    int B, int F) {
  const int r = blockIdx.x;
  const int tid = threadIdx.x;
  const int* conn;
  int id;
  if (r < B) {
    conn = qlc + (size_t)r * 128; id = query[2 * r];
  } else if (r < 2 * B) {
    int b = r - B; conn = qrc + (size_t)b * 128; id = query[2 * b + 1];
  } else if (r < 2 * B + F) {
    int f = r - 2 * B; conn = slc + (size_t)f * 128; id = support[2 * f];
  } else {
    int f = r - 2 * B - F; conn = src_ + (size_t)f * 128; id = support[2 * f + 1];
  }

  __shared__ __align__(16) float cent[256];
  __shared__ float sims[64];
  __shared__ int rel_ids[64];
  __shared__ int ent_ids[64];
  __shared__ unsigned char sel[64];
  __shared__ float red[4];
  __shared__ float cnorm_s;

  if (tid < 64) {
    rel_ids[tid] = conn[2 * tid];
    ent_ids[tid] = conn[2 * tid + 1];
  }
  float cv = emb[(size_t)id * 256 + tid];
  cent[tid] = cv;
  float sq = wave_reduce_sum(cv * cv);
  if ((tid & 63) == 0) red[tid >> 6] = sq;
  __syncthreads();
  if (tid == 0) cnorm_s = sqrtf(red[0] + red[1] + red[2] + red[3]);
  __syncthreads();
  const float cn = cnorm_s;

  const int wave = tid >> 6, lane = tid & 63;
  const float4 cv4 = *(const float4*)(cent + lane * 4);
  for (int n = wave; n < 64; n += 4) {
    const float* er = emb + (size_t)ent_ids[n] * 256;
    float4 e = *(const float4*)(er + lane * 4);
    float d = e.x * cv4.x + e.y * cv4.y + e.z * cv4.z + e.w * cv4.w;
    float s2 = e.x * e.x + e.y * e.y + e.z * e.z + e.w * e.w;
#pragma unroll
    for (int off = 32; off > 0; off >>= 1) {
      d += __shfl_down(d, off, 64);
      s2 += __shfl_down(s2, off, 64);
    }
    if (lane == 0) sims[n] = d / fmaxf(cn * sqrtf(s2), 1e-8f);
  }
  __syncthreads();

  // top-K=32 with stable (lower-index-first) tie-break, matching lax.top_k
  if (tid < 64) {
    float my = sims[tid];
    int rank = 0;
#pragma unroll 8
    for (int j = 0; j < 64; ++j) {
      float sj = sims[j];
      rank += (sj > my) || (sj == my && j < tid);
    }
    sel[tid] = (rank < 32) ? 1 : 0;
  }
  __syncthreads();

  float accR = 0.f, accE = 0.f;
  for (int n = 0; n < 64; ++n) {
    if (sel[n]) {
      accR += emb[(size_t)rel_ids[n] * 256 + tid];
      accE += emb[(size_t)ent_ids[n] * 256 + tid];
    }
  }
  mc[(size_t)r * 512 + tid] = f2bf(accR * (1.f / 32.f));
  mc[(size_t)r * 512 + 256 + tid] = f2bf(accE * (1.f / 32.f));
}

// ------------- bf16 MFMA GEMM_NT: C[i,j] = sum_k A[i,k]*B[j,k] -------------
// Tile 128x128, 256 thr = 2x2 waves, each wave 64x64 via 4x4 of 16x16x32.
// N % 128 == 0, K % 32 == 0, M arbitrary (row-guarded).
// epilogue: v = acc (+bias1[j]) (+bias2[j]) (+addmat[i,j]); act 0/1=tanh/2=relu
// writes fp32 C (if non-null) and/or bf16 Cbf (if non-null).
#define LDSW 40  // LDS row stride in bf16 elems: 80 B, 16B-aligned, 2-way-only
__global__ __launch_bounds__(256) void gemm_bf16_kernel(
    const unsigned short* __restrict__ A, int lda,
    const unsigned short* __restrict__ Bm, int ldb,
    float* __restrict__ C, unsigned short* __restrict__ Cbf,
    int M, int N, int K,
    const float* __restrict__ bias1, const float* __restrict__ bias2,
    const float* __restrict__ addmat, int act) {
  __shared__ __align__(16) unsigned short As[128 * LDSW];
  __shared__ __align__(16) unsigned short Bs[128 * LDSW];
  const int tid = threadIdx.x;
  const int wid = tid >> 6, lane = tid & 63;
  const int quad = lane >> 4, l16 = lane & 15;
  const int wr = (wid >> 1) * 64, wc = (wid & 1) * 64;
  const int row0 = blockIdx.y * 128, col0 = blockIdx.x * 128;

  const int lr = tid >> 1, lc = (tid & 1) * 16;  // staging: row 0..127, col 0/16
  const bool arow_ok = (row0 + lr) < M;
  const unsigned short* Ap = A + (size_t)(row0 + lr) * lda + lc;
  const unsigned short* Bp = Bm + (size_t)(col0 + lr) * ldb + lc;

  floatx4 acc[4][4];
#pragma unroll
  for (int i = 0; i < 4; ++i)
#pragma unroll
    for (int j = 0; j < 4; ++j) {
      floatx4 z = {0.f, 0.f, 0.f, 0.f};
      acc[i][j] = z;
    }

  for (int k0 = 0; k0 < K; k0 += 32) {
    uint4 a0 = make_uint4(0, 0, 0, 0), a1 = make_uint4(0, 0, 0, 0);
    if (arow_ok) {
      a0 = *(const uint4*)(Ap + k0);
      a1 = *(const uint4*)(Ap + k0 + 8);
    }
    uint4 b0 = *(const uint4*)(Bp + k0);
    uint4 b1 = *(const uint4*)(Bp + k0 + 8);
    *(uint4*)&As[lr * LDSW + lc] = a0;
    *(uint4*)&As[lr * LDSW + lc + 8] = a1;
    *(uint4*)&Bs[lr * LDSW + lc] = b0;
    *(uint4*)&Bs[lr * LDSW + lc + 8] = b1;
    __syncthreads();

    short8 af[4], bfr[4];
#pragma unroll
    for (int i = 0; i < 4; ++i)
      af[i] = *(const short8*)&As[(wr + i * 16 + l16) * LDSW + quad * 8];
#pragma unroll
    for (int j = 0; j < 4; ++j)
      bfr[j] = *(const short8*)&Bs[(wc + j * 16 + l16) * LDSW + quad * 8];
#pragma unroll
    for (int i = 0; i < 4; ++i)
#pragma unroll
      for (int j = 0; j < 4; ++j)
        acc[i][j] = __builtin_amdgcn_mfma_f32_16x16x32_bf16(af[i], bfr[j],
                                                            acc[i][j], 0, 0, 0);
    __syncthreads();
  }

  // epilogue: frag(i,j) elem r -> row = wr+i*16+quad*4+r, col = wc+j*16+l16
#pragma unroll
  for (int i = 0; i < 4; ++i) {
#pragma unroll
    for (int r = 0; r < 4; ++r) {
      const int row = row0 + wr + i * 16 + quad * 4 + r;
      if (row >= M) continue;
#pragma unroll
      for (int j = 0; j < 4; ++j) {
        const int col = col0 + wc + j * 16 + l16;
        float v = acc[i][j][r];
        if (bias1) v += bias1[col];
        if (bias2) v += bias2[col];
        if (addmat) v += addmat[(size_t)row * N + col];
        if (act == 1) v = tanhf(v);
        else if (act == 2) v = fmaxf(v, 0.f);
        if (C) C[(size_t)row * N + col] = v;
        if (Cbf) Cbf[(size_t)row * N + col] = f2bf(v);
      }
    }
  }
}

// ------------- fp32 GEMM_NT (kept for tiny M=F support path) ---------------
__global__ __launch_bounds__(256) void gemm_nt_kernel(
    const float* __restrict__ A, int lda, const float* __restrict__ B, int ldb,
    float* __restrict__ C, int M, int N, int K,
    const float* __restrict__ bias1, const float* __restrict__ bias2,
    const float* __restrict__ addmat, int act) {
  __shared__ float As[16][65];
  __shared__ float Bs[16][65];
  const int tid = threadIdx.x;
  const int col0 = blockIdx.x * 64;
  const int row0 = blockIdx.y * 64;
  const int tx = tid & 15, ty = tid >> 4;
  const int lr = tid >> 2, lk = (tid & 3) << 2;

  float acc[4][4];
#pragma unroll
  for (int i = 0; i < 4; ++i)
#pragma unroll
    for (int j = 0; j < 4; ++j) acc[i][j] = 0.f;

  const int ar = row0 + lr;
  const bool avalid = ar < M;
  const float* Aptr = A + (size_t)ar * lda + lk;
  const float* Bptr = B + (size_t)(col0 + lr) * ldb + lk;

  for (int k0 = 0; k0 < K; k0 += 16) {
    float4 av = make_float4(0.f, 0.f, 0.f, 0.f);
    if (avalid) av = *(const float4*)(Aptr + k0);
    float4 bv = *(const float4*)(Bptr + k0);
    As[lk + 0][lr] = av.x; As[lk + 1][lr] = av.y;
    As[lk + 2][lr] = av.z; As[lk + 3][lr] = av.w;
    Bs[lk + 0][lr] = bv.x; Bs[lk + 1][lr] = bv.y;
    Bs[lk + 2][lr] = bv.z; Bs[lk + 3][lr] = bv.w;
    __syncthreads();
#pragma unroll
    for (int k = 0; k < 16; ++k) {
      float a0 = As[k][ty * 4 + 0], a1 = As[k][ty * 4 + 1];
      float a2 = As[k][ty * 4 + 2], a3 = As[k][ty * 4 + 3];
      float b0 = Bs[k][tx * 4 + 0], b1 = Bs[k][tx * 4 + 1];
      float b2 = Bs[k][tx * 4 + 2], b3 = Bs[k][tx * 4 + 3];
      acc[0][0] += a0 * b0; acc[0][1] += a0 * b1; acc[0][2] += a0 * b2; acc[0][3] += a0 * b3;
      acc[1][0] += a1 * b0; acc[1][1] += a1 * b1; acc[1][2] += a1 * b2; acc[1][3] += a1 * b3;
      acc[2][0] += a2 * b0; acc[2][1] += a2 * b1; acc[2][2] += a2 * b2; acc[2][3] += a2 * b3;
      acc[3][0] += a3 * b0; acc[3][1] += a3 * b1; acc[3][2] += a3 * b2; acc[3][3] += a3 * b3;
    }
    __syncthreads();
  }

#pragma unroll
  for (int i = 0; i < 4; ++i) {
    const int r = row0 + ty * 4 + i;
    if (r >= M) continue;
#pragma unroll
    for (int j = 0; j < 4; ++j) {
      const int c = col0 + tx * 4 + j;
      float v = acc[i][j];
      if (bias1) v += bias1[c];
      if (bias2) v += bias2[c];
      if (addmat) v += addmat[(size_t)r * N + c];
      if (act == 1) v = tanhf(v);
      else if (act == 2) v = fmaxf(v, 0.f);
      C[(size_t)r * N + c] = v;
    }
  }
}

// ------------- remap enc (NR x 256) -> qn (B x 512) f32+bf16, sn (F x 512) -
__global__ __launch_bounds__(256) void remap_kernel(
    const float* __restrict__ enc, float* __restrict__ qn,
    unsigned short* __restrict__ qnb, float* __restrict__ sn, int B, int F) {
  const int idx = blockIdx.x * 256 + threadIdx.x;
  const int i = idx >> 8, d = idx & 255;
  const float v = enc[idx];
  if (i < B) {
    qn[(size_t)i * 512 + d] = v;
    qnb[(size_t)i * 512 + d] = f2bf(v);
  } else if (i < 2 * B) {
    qn[(size_t)(i - B) * 512 + 256 + d] = v;
    qnb[(size_t)(i - B) * 512 + 256 + d] = f2bf(v);
  } else if (i < 2 * B + F) {
    sn[(size_t)(i - 2 * B) * 512 + d] = v;
  } else {
    sn[(size_t)(i - 2 * B - F) * 512 + 256 + d] = v;
  }
}

// ------------- LayerNorm rows of 512; optional bf16 copy -------------------
__global__ __launch_bounds__(256) void ln_kernel(
    const float* __restrict__ X, float* __restrict__ Y,
    unsigned short* __restrict__ Ybf,
    const float* __restrict__ g, const float* __restrict__ bta) {
  const int r = blockIdx.x;
  const int tid = threadIdx.x;
  const float* x = X + (size_t)r * 512;
  float x0 = x[tid], x1 = x[tid + 256];
  __shared__ float red[4];
  float s = wave_reduce_sum(x0 + x1);
  if ((tid & 63) == 0) red[tid >> 6] = s;
  __syncthreads();
  const float mean = (red[0] + red[1] + red[2] + red[3]) * (1.f / 512.f);
  __syncthreads();
  const float d0 = x0 - mean, d1 = x1 - mean;
  float v = wave_reduce_sum(d0 * d0 + d1 * d1);
  if ((tid & 63) == 0) red[tid >> 6] = v;
  __syncthreads();
  const float var = (red[0] + red[1] + red[2] + red[3]) * (1.f / 512.f);
  const float inv = 1.f / sqrtf(var + 1e-5f);
  const float y0 = d0 * inv * g[tid] + bta[tid];
  const float y1 = d1 * inv * g[tid + 256] + bta[tid + 256];
  float* y = Y + (size_t)r * 512;
  y[tid] = y0;
  y[tid + 256] = y1;
  if (Ybf) {
    Ybf[(size_t)r * 512 + tid] = f2bf(y0);
    Ybf[(size_t)r * 512 + tid + 256] = f2bf(y1);
  }
}

// ------------- mean over F support rows -> sg (512) ------------------------
__global__ void smean_kernel(const float* __restrict__ ss,
                             float* __restrict__ sg, int F) {
  const int d = blockIdx.x * blockDim.x + threadIdx.x;
  if (d < 512) {
    float s = 0.f;
    for (int f = 0; f < F; ++f) s += ss[(size_t)f * 512 + d];
    sg[d] = s / (float)F;
  }
}

// ------------- cvec[j] = sum_d sg[d] * w_hh[j, 512+d], j < 4096 ------------
__global__ __launch_bounds__(256) void cvec_kernel(
    const float* __restrict__ whh, const float* __restrict__ sg,
    float* __restrict__ cv) {
  const int wave = threadIdx.x >> 6, lane = threadIdx.x & 63;
  const int j = blockIdx.x * 4 + wave;
  const float* wr = whh + (size_t)j * 1024 + 512;
  float s = 0.f;
#pragma unroll
  for (int d = lane; d < 512; d += 64) s += wr[d] * sg[d];
  s = wave_reduce_sum(s);
  if (lane == 0) cv[j] = s;
}

// ------------- LSTM cell elementwise; h in f32 + bf16 ----------------------
__global__ __launch_bounds__(256) void cell_kernel(
    const float* __restrict__ gates, float* __restrict__ c,
    const float* __restrict__ qg, float* __restrict__ h,
    unsigned short* __restrict__ hbf, int first) {
  const size_t idx = (size_t)blockIdx.x * 256 + threadIdx.x;
  const int b = (int)(idx >> 10), n = (int)(idx & 1023);
  const float* gr = gates + (size_t)b * 4096;
  const float gi = gr[n], gf = gr[1024 + n], gg = gr[2048 + n], go = gr[3072 + n];
  const float cold = first ? 0.f : c[idx];
  const float si = 1.f / (1.f + expf(-gi));
  const float sf = 1.f / (1.f + expf(-gf));
  const float cn = sf * cold + si * tanhf(gg);
  c[idx] = cn;
  if (n < 512) {
    const float so = 1.f / (1.f + expf(-go));
    const float hv = qg[(size_t)b * 512 + n] + so * tanhf(cn);
    h[(size_t)b * 512 + n] = hv;
    hbf[(size_t)b * 512 + n] = f2bf(hv);
  }
}

// ------------- out[b] = cosine(h[b], sg) -----------------------------------
__global__ __launch_bounds__(256) void final_kernel(
    const float* __restrict__ h, const float* __restrict__ sg,
    float* __restrict__ out) {
  const int b = blockIdx.x, tid = threadIdx.x;
  const float* hr = h + (size_t)b * 512;
  const float h0 = hr[tid], h1 = hr[tid + 256];
  const float s0 = sg[tid], s1 = sg[tid + 256];
  float d = h0 * s0 + h1 * s1;
  float hh = h0 * h0 + h1 * h1;
  float ssq = s0 * s0 + s1 * s1;
  __shared__ float red[3][4];
  d = wave_reduce_sum(d);
  hh = wave_reduce_sum(hh);
  ssq = wave_reduce_sum(ssq);
  if ((tid & 63) == 0) {
    red[0][tid >> 6] = d; red[1][tid >> 6] = hh; red[2][tid >> 6] = ssq;
  }
  __syncthreads();
  if (tid == 0) {
    const float D = red[0][0] + red[0][1] + red[0][2] + red[0][3];
    const float H = red[1][0] + red[1][1] + red[1][2] + red[1][3];
    const float S = red[2][0] + red[2][1] + red[2][2] + red[2][3];
    out[b] = D / (fmaxf(sqrtf(H), 1e-12f) * fmaxf(sqrtf(S), 1e-12f));
  }
}

extern "C" void kernel_launch(void* const* d_in, const int* in_sizes, int n_in,
                              void* d_out, int out_size, void* d_ws, size_t ws_size,
                              hipStream_t stream) {
  const int* query = (const int*)d_in[0];
  const int* support = (const int*)d_in[1];
  const int* qlc = (const int*)d_in[2];
  const int* qrc = (const int*)d_in[4];
  const int* slc = (const int*)d_in[6];
  const int* src_ = (const int*)d_in[8];
  const float* emb = (const float*)d_in[10];
  const float* gcn_w = (const float*)d_in[11];
  const float* gcn_wb = (const float*)d_in[12];
  const float* gcn_b = (const float*)d_in[13];
  const float* p1_w = (const float*)d_in[14];
  const float* p1_b = (const float*)d_in[15];
  const float* p2_w = (const float*)d_in[16];
  const float* p2_b = (const float*)d_in[17];
  const float* ln_g = (const float*)d_in[18];
  const float* ln_b = (const float*)d_in[19];
  const float* w_ih = (const float*)d_in[20];
  const float* w_hh = (const float*)d_in[21];
  const float* b_ih = (const float*)d_in[22];
  const float* b_hh = (const float*)d_in[23];
  float* out = (float*)d_out;

  const int B = in_sizes[0] / 2;   // 2048
  const int F = in_sizes[1] / 2;   // 5
  const int NR = 2 * B + 2 * F;    // 4106

  // ---- workspace layout (bytes, 256-aligned), time-disjoint aliasing -----
  char* Wb = (char*)d_ws;
  size_t off = 0;
  auto alloc = [&](size_t bytes) {
    size_t o = off;
    off += (bytes + 255) & ~(size_t)255;
    return o;
  };
  const size_t base_o = alloc((size_t)B * 4096 * 4);   // f32, lives to end
  const size_t gates_o = alloc((size_t)B * 4096 * 4);  // f32, steps 1..3
  // early-phase buffers alias into the gates region (all dead before step 1):
  const size_t mc_o   = gates_o;                         // NR*512 bf16
  const size_t enc_o  = mc_o  + (((size_t)NR * 512 * 2 + 255) & ~(size_t)255);
  const size_t qn_o   = enc_o + (((size_t)NR * 256 * 4 + 255) & ~(size_t)255);
  const size_t qnb_o  = qn_o  + (((size_t)B * 512 * 4 + 255) & ~(size_t)255);
  const size_t hqb_o  = qnb_o + (((size_t)B * 512 * 2 + 255) & ~(size_t)255);
  const size_t oq_o   = hqb_o + (((size_t)B * 1024 * 2 + 255) & ~(size_t)255);
  // (mc+enc+qn+qnb+hqb+oq ~= 23.1 MB < 33.55 MB gates region)
  const size_t qg_o   = alloc((size_t)B * 512 * 4);
  const size_t qgb_o  = alloc((size_t)B * 512 * 2);
  const size_t cbuf_o = alloc((size_t)B * 1024 * 4);
  const size_t h_o    = alloc((size_t)B * 512 * 4);
  const size_t hb_o   = alloc((size_t)B * 512 * 2);
  const size_t wihb_o = alloc((size_t)4096 * 512 * 2);
  const size_t whhb_o = alloc((size_t)4096 * 512 * 2);
  const size_t p1b_o  = alloc((size_t)1024 * 512 * 2);
  const size_t p2b_o  = alloc((size_t)512 * 1024 * 2);
  const size_t gcnb_o = alloc((size_t)256 * 512 * 2);
  const size_t sn_o   = alloc((size_t)F * 512 * 4);
  const size_t hs_o   = alloc((size_t)F * 1024 * 4);
  const size_t oss_o  = alloc((size_t)F * 512 * 4);
  const size_t ssb_o  = alloc((size_t)F * 512 * 4);
  const size_t sg_o   = alloc(512 * 4);
  const size_t cvec_o = alloc(4096 * 4);
  // total ~= 99 MB

  auto F32 = [&](size_t o) { return (float*)(Wb + o); };
  auto BF = [&](size_t o) { return (unsigned short*)(Wb + o); };

  auto gemm_bf = [&](const unsigned short* A, int lda, const unsigned short* Bm,
                     int ldb, float* C, unsigned short* Cbf, int M, int N,
                     int K, const float* b1, const float* b2, const float* add,
                     int act) {
    dim3 g(N / 128, (M + 127) / 128);
    gemm_bf16_kernel<<<g, 256, 0, stream>>>(A, lda, Bm, ldb, C, Cbf, M, N, K,
                                            b1, b2, add, act);
  };
  auto gemm_f32 = [&](const float* A, int lda, const float* Bm, int ldb,
                      float* C, int M, int N, int K, const float* b1,
                      const float* b2, const float* add, int act) {
    dim3 g(N / 64, (M + 63) / 64);
    gemm_nt_kernel<<<g, 256, 0, stream>>>(A, lda, Bm, ldb, C, M, N, K, b1, b2,
                                          add, act);
  };
  auto conv = [&](const float* in, int ld, int cols, unsigned short* o, int tot) {
    convert_bf16_kernel<<<(tot + 255) / 256, 256, 0, stream>>>(in, ld, cols, o,
                                                               tot);
  };

  // 0. weight conversions (every call; ws is re-poisoned by harness)
  conv(w_ih, 512, 512, BF(wihb_o), 4096 * 512);
  conv(w_hh, 1024, 512, BF(whhb_o), 4096 * 512);  // only cols [0,512)
  conv(p1_w, 512, 512, BF(p1b_o), 1024 * 512);
  conv(p2_w, 1024, 1024, BF(p2b_o), 512 * 1024);
  conv(gcn_w, 512, 512, BF(gcnb_o), 256 * 512);

  // 1. neighbor encoder -> mc (NR x 512, bf16)
  neighbor_kernel<<<NR, 256, 0, stream>>>(query, support, qlc, qrc, slc, src_,
                                          emb, BF(mc_o), B, F);
  // 2. GCN: enc = tanh(mc @ gcn_w^T + gcn_wb + gcn_b)   (NR x 256, f32)
  gemm_bf(BF(mc_o), 512, BF(gcnb_o), 512, F32(enc_o), nullptr, NR, 256, 512,
          gcn_wb, gcn_b, nullptr, 1);
  // 3. remap -> qn f32+bf16 (B x 512), sn f32 (F x 512)
  remap_kernel<<<NR, 256, 0, stream>>>(F32(enc_o), F32(qn_o), BF(qnb_o),
                                       F32(sn_o), B, F);
  // 4-5. support_encoder(queries): bf16 MFMA
  gemm_bf(BF(qnb_o), 512, BF(p1b_o), 512, nullptr, BF(hqb_o), B, 1024, 512,
          p1_b, nullptr, nullptr, 2);
  gemm_bf(BF(hqb_o), 1024, BF(p2b_o), 1024, F32(oq_o), nullptr, B, 512, 1024,
          p2_b, nullptr, F32(qn_o), 0);
  // 6-7. support_encoder(supports): fp32 (M=5, tiny)
  gemm_f32(F32(sn_o), 512, p1_w, 512, F32(hs_o), F, 1024, 512, p1_b, nullptr,
           nullptr, 2);
  gemm_f32(F32(hs_o), 1024, p2_w, 1024, F32(oss_o), F, 512, 1024, p2_b,
           nullptr, F32(sn_o), 0);
  // 8. LN supports + mean -> sg
  ln_kernel<<<F, 256, 0, stream>>>(F32(oss_o), F32(ssb_o), nullptr, ln_g, ln_b);
  smean_kernel<<<2, 256, 0, stream>>>(F32(ssb_o), F32(sg_o), F);
  // 9. LN queries -> qg f32 + bf16
  ln_kernel<<<B, 256, 0, stream>>>(F32(oq_o), F32(qg_o), BF(qgb_o), ln_g, ln_b);
  // 10. base = qg @ w_ih^T + b_ih + b_hh  (B x 4096)
  gemm_bf(BF(qgb_o), 512, BF(wihb_o), 512, F32(base_o), nullptr, B, 4096, 512,
          b_ih, b_hh, nullptr, 0);
  // 11. cvec = sg @ w_hh[:,512:]^T  (4096)
  cvec_kernel<<<1024, 256, 0, stream>>>(w_hh, F32(sg_o), F32(cvec_o));
  // 12. LSTM step 0 (h_r = 0 -> gates == base)
  cell_kernel<<<(B * 1024) / 256, 256, 0, stream>>>(
      F32(base_o), F32(cbuf_o), F32(qg_o), F32(h_o), BF(hb_o), 1);
  // 13-16. steps 1..3
  for (int s = 1; s < 4; ++s) {
    gemm_bf(BF(hb_o), 512, BF(whhb_o), 512, F32(gates_o), nullptr, B, 4096,
            512, F32(cvec_o), nullptr, F32(base_o), 0);
    cell_kernel<<<(B * 1024) / 256, 256, 0, stream>>>(
        F32(gates_o), F32(cbuf_o), F32(qg_o), F32(h_o), BF(hb_o), 0);
  }
  // 17. output
  final_kernel<<<B, 256, 0, stream>>>(F32(h_o), F32(sg_o), out);
}

// Round 3
// 804.890 us; speedup vs baseline: 1.8165x; 1.1198x over previous
//
#include <hip/hip_runtime.h>
#include <math.h>

// ---------------------------------------------------------------------------
// EmbedMatcher: V=200000 D=256 B=2048 F=5 N=64 K=32 DM=512 HID=1024 STEPS=4
// Simplifications (verified vs reference):
//  * GCN mean commutes with linear layer
//  * attn = softmax over ONE column == 1 -> r == support_g (constant)
//  * gates = base + h @ Whh[:, :512]^T + cvec; base/cvec step-invariant
//  * step 0: h_r = 0 -> gates == base
// Round 3: neighbor caches ent rows in LDS + branchless compacted top-K;
// LSTM cell fused into GEMM epilogues via gate-interleaved weight permutation
// (dst row c <- orig row gate*1024+n, gate=(c>>4)&3, n=(c>>6)*16+(c&15), so a
// lane's 4 j-fragments are the i,f,g,o quad of one n); 64x64-tile GEMM for
// small-grid GEMMs (GCN epilogue fuses remap); single fused convert kernel.
// ---------------------------------------------------------------------------

typedef __attribute__((ext_vector_type(8))) short short8;
typedef __attribute__((ext_vector_type(4))) float floatx4;

__device__ inline unsigned short f2bf(float f) {
  union { float f; unsigned int u; } x;
  x.f = f;
  unsigned int r = x.u + 0x7fffu + ((x.u >> 16) & 1u);  // RNE
  return (unsigned short)(r >> 16);
}
__device__ inline float bf2f(unsigned short u) {
  union { unsigned int i; float f; } x;
  x.i = ((unsigned int)u) << 16;
  return x.f;
}
__device__ inline float sigm(float x) { return 1.f / (1.f + expf(-x)); }

__device__ inline float wave_reduce_sum(float v) {
#pragma unroll
  for (int off = 32; off > 0; off >>= 1) v += __shfl_down(v, off, 64);
  return v;
}

// ---------------- fused weight convert + permute (one launch) --------------
// pack boundaries (float4 units): w_ih 524288 | w_hh 524288 | p1 131072 |
// p2 131072 | gcn 32768 | bias 1024  -> total 1344512 packs, grid 5252.
__global__ __launch_bounds__(256) void convert_all_kernel(
    const float* __restrict__ w_ih, const float* __restrict__ w_hh,
    const float* __restrict__ p1_w, const float* __restrict__ p2_w,
    const float* __restrict__ gcn_w, const float* __restrict__ b_ih,
    const float* __restrict__ b_hh, unsigned short* __restrict__ wihb,
    unsigned short* __restrict__ whhb, unsigned short* __restrict__ p1b,
    unsigned short* __restrict__ p2b, unsigned short* __restrict__ gcnb,
    float* __restrict__ bcomb) {
  const int p = blockIdx.x * 256 + threadIdx.x;
  if (p < 524288) {
    const int e = p * 4, r = e >> 9, c = e & 511;
    const int orig = ((r >> 4) & 3) * 1024 + ((r >> 6) << 4) + (r & 15);
    float4 v = *(const float4*)(w_ih + (size_t)orig * 512 + c);
    *(ushort4*)(wihb + (size_t)r * 512 + c) =
        make_ushort4(f2bf(v.x), f2bf(v.y), f2bf(v.z), f2bf(v.w));
  } else if (p < 1048576) {
    const int e = (p - 524288) * 4, r = e >> 9, c = e & 511;
    const int orig = ((r >> 4) & 3) * 1024 + ((r >> 6) << 4) + (r & 15);
    float4 v = *(const float4*)(w_hh + (size_t)orig * 1024 + c);
    *(ushort4*)(whhb + (size_t)r * 512 + c) =
        make_ushort4(f2bf(v.x), f2bf(v.y), f2bf(v.z), f2bf(v.w));
  } else if (p < 1179648) {
    const int e = (p - 1048576) * 4;
    float4 v = *(const float4*)(p1_w + e);
    *(ushort4*)(p1b + e) =
        make_ushort4(f2bf(v.x), f2bf(v.y), f2bf(v.z), f2bf(v.w));
  } else if (p < 1310720) {
    const int e = (p - 1179648) * 4;
    float4 v = *(const float4*)(p2_w + e);
    *(ushort4*)(p2b + e) =
        make_ushort4(f2bf(v.x), f2bf(v.y), f2bf(v.z), f2bf(v.w));
  } else if (p < 1343488) {
    const int e = (p - 1310720) * 4;
    float4 v = *(const float4*)(gcn_w + e);
    *(ushort4*)(gcnb + e) =
        make_ushort4(f2bf(v.x), f2bf(v.y), f2bf(v.z), f2bf(v.w));
  } else if (p < 1344512) {
    const int c = (p - 1343488) * 4;
    const int orig = ((c >> 4) & 3) * 1024 + ((c >> 6) << 4) + (c & 15);
    float4 a = *(const float4*)(b_ih + orig);
    float4 b = *(const float4*)(b_hh + orig);
    *(float4*)(bcomb + c) =
        make_float4(a.x + b.x, a.y + b.y, a.z + b.z, a.w + b.w);
  }
}

// ---------------- neighbor encoder v2: LDS ent cache + compacted top-K -----
__global__ __launch_bounds__(256) void neighbor_kernel(
    const int* __restrict__ query, const int* __restrict__ support,
    const int* __restrict__ qlc, const int* __restrict__ qrc,
    const int* __restrict__ slc, const int* __restrict__ src_,
    const float* __restrict__ emb, unsigned short* __restrict__ mc,
    int B, int F) {
  const int r = blockIdx.x;
  const int tid = threadIdx.x;
  const int* conn;
  int id;
  if (r < B) {
    conn = qlc + (size_t)r * 128; id = query[2 * r];
  } else if (r < 2 * B) {
    int b = r - B; conn = qrc + (size_t)b * 128; id = query[2 * b + 1];
  } else if (r < 2 * B + F) {
    int f = r - 2 * B; conn = slc + (size_t)f * 128; id = support[2 * f];
  } else {
    int f = r - 2 * B - F; conn = src_ + (size_t)f * 128; id = support[2 * f + 1];
  }

  __shared__ __align__(16) float cent[256];
  __shared__ __align__(16) unsigned short entl[64 * 256];  // 32 KB bf16 cache
  __shared__ float sims[64];
  __shared__ int rel_ids[64];
  __shared__ int ent_ids[64];
  __shared__ short list[32];
  __shared__ float red[4];
  __shared__ float cnorm_s;

  if (tid < 64) {
    rel_ids[tid] = conn[2 * tid];
    ent_ids[tid] = conn[2 * tid + 1];
  }
  float cv = emb[(size_t)id * 256 + tid];
  cent[tid] = cv;
  float sq = wave_reduce_sum(cv * cv);
  if ((tid & 63) == 0) red[tid >> 6] = sq;
  __syncthreads();
  if (tid == 0) cnorm_s = sqrtf(red[0] + red[1] + red[2] + red[3]);
  __syncthreads();
  const float cn = cnorm_s;

  const int wave = tid >> 6, lane = tid & 63;
  const float4 cv4 = *(const float4*)(cent + lane * 4);
#pragma unroll 2
  for (int n = wave; n < 64; n += 4) {
    const float* er = emb + (size_t)ent_ids[n] * 256;
    float4 e = *(const float4*)(er + lane * 4);
    *(ushort4*)&entl[n * 256 + lane * 4] =
        make_ushort4(f2bf(e.x), f2bf(e.y), f2bf(e.z), f2bf(e.w));
    float d = e.x * cv4.x + e.y * cv4.y + e.z * cv4.z + e.w * cv4.w;
    float s2 = e.x * e.x + e.y * e.y + e.z * e.z + e.w * e.w;
#pragma unroll
    for (int off = 32; off > 0; off >>= 1) {
      d += __shfl_down(d, off, 64);
      s2 += __shfl_down(s2, off, 64);
    }
    if (lane == 0) sims[n] = d / fmaxf(cn * sqrtf(s2), 1e-8f);
  }
  __syncthreads();

  // top-K=32, stable tie-break (lower index first) == lax.top_k; ranks unique
  if (tid < 64) {
    float my = sims[tid];
    int rank = 0;
#pragma unroll 8
    for (int j = 0; j < 64; ++j) {
      float sj = sims[j];
      rank += (sj > my) || (sj == my && j < tid);
    }
    if (rank < 32) list[rank] = (short)tid;
  }
  __syncthreads();

  float accR = 0.f, accE = 0.f;
  for (int k = 0; k < 32; k += 4) {
    const int n0 = list[k], n1 = list[k + 1], n2 = list[k + 2], n3 = list[k + 3];
    const float* p0 = emb + (size_t)rel_ids[n0] * 256;
    const float* p1 = emb + (size_t)rel_ids[n1] * 256;
    const float* p2 = emb + (size_t)rel_ids[n2] * 256;
    const float* p3 = emb + (size_t)rel_ids[n3] * 256;
    const float r0 = p0[tid], r1 = p1[tid], r2 = p2[tid], r3 = p3[tid];
    const float e0 = bf2f(entl[n0 * 256 + tid]);
    const float e1 = bf2f(entl[n1 * 256 + tid]);
    const float e2 = bf2f(entl[n2 * 256 + tid]);
    const float e3 = bf2f(entl[n3 * 256 + tid]);
    accR += (r0 + r1) + (r2 + r3);
    accE += (e0 + e1) + (e2 + e3);
  }
  mc[(size_t)r * 512 + tid] = f2bf(accR * (1.f / 32.f));
  mc[(size_t)r * 512 + 256 + tid] = f2bf(accE * (1.f / 32.f));
}

// ------------- bf16 MFMA GEMM_NT 128x128; modes: 0 normal, 1 base+cell0,
// ------------- 2 step+cell.  N%128==0, K%32==0, M row-guarded.
#define LDSW 40
__global__ __launch_bounds__(256) void gemm128_kernel(
    const unsigned short* __restrict__ A, int lda,
    const unsigned short* __restrict__ Bm, int ldb,
    float* __restrict__ C, unsigned short* __restrict__ Cbf,
    int M, int N, int K,
    const float* __restrict__ bias1, const float* __restrict__ bias2,
    const float* __restrict__ addmat, int act, int mode,
    float* __restrict__ cbuf, const float* __restrict__ qg,
    float* __restrict__ h, unsigned short* __restrict__ hbf) {
  __shared__ __align__(16) unsigned short As[128 * LDSW];
  __shared__ __align__(16) unsigned short Bs[128 * LDSW];
  const int tid = threadIdx.x;
  const int wid = tid >> 6, lane = tid & 63;
  const int quad = lane >> 4, l16 = lane & 15;
  const int wr = (wid >> 1) * 64, wc = (wid & 1) * 64;
  const int row0 = blockIdx.y * 128, col0 = blockIdx.x * 128;

  const int lr = tid >> 1, lc = (tid & 1) * 16;
  const bool arow_ok = (row0 + lr) < M;
  const unsigned short* Ap = A + (size_t)(row0 + lr) * lda + lc;
  const unsigned short* Bp = Bm + (size_t)(col0 + lr) * ldb + lc;

  floatx4 acc[4][4];
#pragma unroll
  for (int i = 0; i < 4; ++i)
#pragma unroll
    for (int j = 0; j < 4; ++j) {
      floatx4 z = {0.f, 0.f, 0.f, 0.f};
      acc[i][j] = z;
    }

  for (int k0 = 0; k0 < K; k0 += 32) {
    uint4 a0 = make_uint4(0, 0, 0, 0), a1 = make_uint4(0, 0, 0, 0);
    if (arow_ok) {
      a0 = *(const uint4*)(Ap + k0);
      a1 = *(const uint4*)(Ap + k0 + 8);
    }
    uint4 b0 = *(const uint4*)(Bp + k0);
    uint4 b1 = *(const uint4*)(Bp + k0 + 8);
    *(uint4*)&As[lr * LDSW + lc] = a0;
    *(uint4*)&As[lr * LDSW + lc + 8] = a1;
    *(uint4*)&Bs[lr * LDSW + lc] = b0;
    *(uint4*)&Bs[lr * LDSW + lc + 8] = b1;
    __syncthreads();

    short8 af[4], bfr[4];
#pragma unroll
    for (int i = 0; i < 4; ++i)
      af[i] = *(const short8*)&As[(wr + i * 16 + l16) * LDSW + quad * 8];
#pragma unroll
    for (int j = 0; j < 4; ++j)
      bfr[j] = *(const short8*)&Bs[(wc + j * 16 + l16) * LDSW + quad * 8];
#pragma unroll
    for (int i = 0; i < 4; ++i)
#pragma unroll
      for (int j = 0; j < 4; ++j)
        acc[i][j] = __builtin_amdgcn_mfma_f32_16x16x32_bf16(af[i], bfr[j],
                                                            acc[i][j], 0, 0, 0);
    __syncthreads();
  }

#pragma unroll
  for (int i = 0; i < 4; ++i) {
#pragma unroll
    for (int r = 0; r < 4; ++r) {
      const int row = row0 + wr + i * 16 + quad * 4 + r;
      if (row >= M) continue;
      float vals[4];
#pragma unroll
      for (int j = 0; j < 4; ++j) {
        const int col = col0 + wc + j * 16 + l16;
        float v = acc[i][j][r];
        if (bias1) v += bias1[col];
        if (bias2) v += bias2[col];
        if (addmat) v += addmat[(size_t)row * N + col];
        vals[j] = v;
      }
      if (mode == 0) {
#pragma unroll
        for (int j = 0; j < 4; ++j) {
          const int col = col0 + wc + j * 16 + l16;
          float v = vals[j];
          if (act == 1) v = tanhf(v);
          else if (act == 2) v = fmaxf(v, 0.f);
          if (C) C[(size_t)row * N + col] = v;
          if (Cbf) Cbf[(size_t)row * N + col] = f2bf(v);
        }
      } else {
        if (mode == 1) {
#pragma unroll
          for (int j = 0; j < 4; ++j)
            C[(size_t)row * N + (col0 + wc + j * 16 + l16)] = vals[j];
        }
        // j == gate (i,f,g,o) of gate-index n, by weight-row permutation
        const int n = (((col0 + wc) >> 6) << 4) + l16;
        const float cold = (mode == 1) ? 0.f : cbuf[(size_t)row * 1024 + n];
        const float cn = sigm(vals[1]) * cold + sigm(vals[0]) * tanhf(vals[2]);
        cbuf[(size_t)row * 1024 + n] = cn;
        if (n < 512) {
          const float hv =
              qg[(size_t)row * 512 + n] + sigm(vals[3]) * tanhf(cn);
          h[(size_t)row * 512 + n] = hv;
          hbf[(size_t)row * 512 + n] = f2bf(hv);
        }
      }
    }
  }
}

// ------------- bf16 MFMA GEMM_NT 64x64 (high-occupancy small GEMMs) --------
// snptr != null => GCN remap epilogue (scatter rows to qn/qnb/sn).
__global__ __launch_bounds__(256) void gemm64_kernel(
    const unsigned short* __restrict__ A, int lda,
    const unsigned short* __restrict__ Bm, int ldb,
    float* __restrict__ C, unsigned short* __restrict__ Cbf,
    int M, int N, int K,
    const float* __restrict__ bias1, const float* __restrict__ bias2,
    const float* __restrict__ addmat, int act, int rB, int rF,
    float* __restrict__ snptr) {
  __shared__ __align__(16) unsigned short As[64 * LDSW];
  __shared__ __align__(16) unsigned short Bs[64 * LDSW];
  const int tid = threadIdx.x;
  const int wid = tid >> 6, lane = tid & 63;
  const int quad = lane >> 4, l16 = lane & 15;
  const int wr = (wid >> 1) * 32, wc = (wid & 1) * 32;
  const int row0 = blockIdx.y * 64, col0 = blockIdx.x * 64;

  const int t = tid & 127;
  const int lr = t >> 1, lc = (t & 1) * 16;
  const bool isA = tid < 128;
  const bool row_ok = isA ? (row0 + lr) < M : true;
  const unsigned short* P = isA ? (A + (size_t)(row0 + lr) * lda + lc)
                                : (Bm + (size_t)(col0 + lr) * ldb + lc);
  unsigned short* S = (isA ? As : Bs) + lr * LDSW + lc;

  floatx4 acc[2][2];
#pragma unroll
  for (int i = 0; i < 2; ++i)
#pragma unroll
    for (int j = 0; j < 2; ++j) {
      floatx4 z = {0.f, 0.f, 0.f, 0.f};
      acc[i][j] = z;
    }

  for (int k0 = 0; k0 < K; k0 += 32) {
    uint4 v0 = make_uint4(0, 0, 0, 0), v1 = make_uint4(0, 0, 0, 0);
    if (row_ok) {
      v0 = *(const uint4*)(P + k0);
      v1 = *(const uint4*)(P + k0 + 8);
    }
    *(uint4*)S = v0;
    *(uint4*)(S + 8) = v1;
    __syncthreads();

    short8 af[2], bfr[2];
#pragma unroll
    for (int i = 0; i < 2; ++i)
      af[i] = *(const short8*)&As[(wr + i * 16 + l16) * LDSW + quad * 8];
#pragma unroll
    for (int j = 0; j < 2; ++j)
      bfr[j] = *(const short8*)&Bs[(wc + j * 16 + l16) * LDSW + quad * 8];
#pragma unroll
    for (int i = 0; i < 2; ++i)
#pragma unroll
      for (int j = 0; j < 2; ++j)
        acc[i][j] = __builtin_amdgcn_mfma_f32_16x16x32_bf16(af[i], bfr[j],
                                                            acc[i][j], 0, 0, 0);
    __syncthreads();
  }

#pragma unroll
  for (int i = 0; i < 2; ++i) {
#pragma unroll
    for (int r = 0; r < 4; ++r) {
      const int row = row0 + wr + i * 16 + quad * 4 + r;
      if (row >= M) continue;
#pragma unroll
      for (int j = 0; j < 2; ++j) {
        const int col = col0 + wc + j * 16 + l16;
        float v = acc[i][j][r];
        if (bias1) v += bias1[col];
        if (bias2) v += bias2[col];
        if (addmat) v += addmat[(size_t)row * N + col];
        if (act == 1) v = tanhf(v);
        else if (act == 2) v = fmaxf(v, 0.f);
        if (snptr) {  // GCN remap: row -> {qn | qn+256 | sn | sn+256}
          if (row < rB) {
            C[(size_t)row * 512 + col] = v;
            Cbf[(size_t)row * 512 + col] = f2bf(v);
          } else if (row < 2 * rB) {
            C[(size_t)(row - rB) * 512 + 256 + col] = v;
            Cbf[(size_t)(row - rB) * 512 + 256 + col] = f2bf(v);
          } else if (row < 2 * rB + rF) {
            snptr[(size_t)(row - 2 * rB) * 512 + col] = v;
          } else {
            snptr[(size_t)(row - 2 * rB - rF) * 512 + 256 + col] = v;
          }
        } else {
          if (C) C[(size_t)row * N + col] = v;
          if (Cbf) Cbf[(size_t)row * N + col] = f2bf(v);
        }
      }
    }
  }
}

// ------------- fp32 GEMM_NT (tiny M=F support path) ------------------------
__global__ __launch_bounds__(256) void gemm_nt_kernel(
    const float* __restrict__ A, int lda, const float* __restrict__ B, int ldb,
    float* __restrict__ C, int M, int N, int K,
    const float* __restrict__ bias1, const float* __restrict__ bias2,
    const float* __restrict__ addmat, int act) {
  __shared__ float As[16][65];
  __shared__ float Bs[16][65];
  const int tid = threadIdx.x;
  const int col0 = blockIdx.x * 64;
  const int row0 = blockIdx.y * 64;
  const int tx = tid & 15, ty = tid >> 4;
  const int lr = tid >> 2, lk = (tid & 3) << 2;

  float acc[4][4];
#pragma unroll
  for (int i = 0; i < 4; ++i)
#pragma unroll
    for (int j = 0; j < 4; ++j) acc[i][j] = 0.f;

  const int ar = row0 + lr;
  const bool avalid = ar < M;
  const float* Aptr = A + (size_t)ar * lda + lk;
  const float* Bptr = B + (size_t)(col0 + lr) * ldb + lk;

  for (int k0 = 0; k0 < K; k0 += 16) {
    float4 av = make_float4(0.f, 0.f, 0.f, 0.f);
    if (avalid) av = *(const float4*)(Aptr + k0);
    float4 bv = *(const float4*)(Bptr + k0);
    As[lk + 0][lr] = av.x; As[lk + 1][lr] = av.y;
    As[lk + 2][lr] = av.z; As[lk + 3][lr] = av.w;
    Bs[lk + 0][lr] = bv.x; Bs[lk + 1][lr] = bv.y;
    Bs[lk + 2][lr] = bv.z; Bs[lk + 3][lr] = bv.w;
    __syncthreads();
#pragma unroll
    for (int k = 0; k < 16; ++k) {
      float a0 = As[k][ty * 4 + 0], a1 = As[k][ty * 4 + 1];
      float a2 = As[k][ty * 4 + 2], a3 = As[k][ty * 4 + 3];
      float b0 = Bs[k][tx * 4 + 0], b1 = Bs[k][tx * 4 + 1];
      float b2 = Bs[k][tx * 4 + 2], b3 = Bs[k][tx * 4 + 3];
      acc[0][0] += a0 * b0; acc[0][1] += a0 * b1; acc[0][2] += a0 * b2; acc[0][3] += a0 * b3;
      acc[1][0] += a1 * b0; acc[1][1] += a1 * b1; acc[1][2] += a1 * b2; acc[1][3] += a1 * b3;
      acc[2][0] += a2 * b0; acc[2][1] += a2 * b1; acc[2][2] += a2 * b2; acc[2][3] += a2 * b3;
      acc[3][0] += a3 * b0; acc[3][1] += a3 * b1; acc[3][2] += a3 * b2; acc[3][3] += a3 * b3;
    }
    __syncthreads();
  }

#pragma unroll
  for (int i = 0; i < 4; ++i) {
    const int r = row0 + ty * 4 + i;
    if (r >= M) continue;
#pragma unroll
    for (int j = 0; j < 4; ++j) {
      const int c = col0 + tx * 4 + j;
      float v = acc[i][j];
      if (bias1) v += bias1[c];
      if (bias2) v += bias2[c];
      if (addmat) v += addmat[(size_t)r * N + c];
      if (act == 1) v = tanhf(v);
      else if (act == 2) v = fmaxf(v, 0.f);
      C[(size_t)r * N + c] = v;
    }
  }
}

// ------------- LayerNorm rows of 512; optional bf16 copy -------------------
__global__ __launch_bounds__(256) void ln_kernel(
    const float* __restrict__ X, float* __restrict__ Y,
    unsigned short* __restrict__ Ybf,
    const float* __restrict__ g, const float* __restrict__ bta) {
  const int r = blockIdx.x;
  const int tid = threadIdx.x;
  const float* x = X + (size_t)r * 512;
  float x0 = x[tid], x1 = x[tid + 256];
  __shared__ float red[4];
  float s = wave_reduce_sum(x0 + x1);
  if ((tid & 63) == 0) red[tid >> 6] = s;
  __syncthreads();
  const float mean = (red[0] + red[1] + red[2] + red[3]) * (1.f / 512.f);
  __syncthreads();
  const float d0 = x0 - mean, d1 = x1 - mean;
  float v = wave_reduce_sum(d0 * d0 + d1 * d1);
  if ((tid & 63) == 0) red[tid >> 6] = v;
  __syncthreads();
  const float var = (red[0] + red[1] + red[2] + red[3]) * (1.f / 512.f);
  const float inv = 1.f / sqrtf(var + 1e-5f);
  const float y0 = d0 * inv * g[tid] + bta[tid];
  const float y1 = d1 * inv * g[tid + 256] + bta[tid + 256];
  float* y = Y + (size_t)r * 512;
  y[tid] = y0;
  y[tid + 256] = y1;
  if (Ybf) {
    Ybf[(size_t)r * 512 + tid] = f2bf(y0);
    Ybf[(size_t)r * 512 + tid + 256] = f2bf(y1);
  }
}

// ------------- mean over F support rows -> sg (512) ------------------------
__global__ void smean_kernel(const float* __restrict__ ss,
                             float* __restrict__ sg, int F) {
  const int d = blockIdx.x * blockDim.x + threadIdx.x;
  if (d < 512) {
    float s = 0.f;
    for (int f = 0; f < F; ++f) s += ss[(size_t)f * 512 + d];
    sg[d] = s / (float)F;
  }
}

// ------------- cvec[jp] = sum_d sg[d] * w_hh[orig(jp), 512+d] (permuted) ---
__global__ __launch_bounds__(256) void cvec_kernel(
    const float* __restrict__ whh, const float* __restrict__ sg,
    float* __restrict__ cv) {
  const int wave = threadIdx.x >> 6, lane = threadIdx.x & 63;
  const int jp = blockIdx.x * 4 + wave;
  const int orig = ((jp >> 4) & 3) * 1024 + ((jp >> 6) << 4) + (jp & 15);
  const float* wr = whh + (size_t)orig * 1024 + 512;
  float s = 0.f;
#pragma unroll
  for (int d = lane; d < 512; d += 64) s += wr[d] * sg[d];
  s = wave_reduce_sum(s);
  if (lane == 0) cv[jp] = s;
}

// ------------- out[b] = cosine(h[b], sg) -----------------------------------
__global__ __launch_bounds__(256) void final_kernel(
    const float* __restrict__ h, const float* __restrict__ sg,
    float* __restrict__ out) {
  const int b = blockIdx.x, tid = threadIdx.x;
  const float* hr = h + (size_t)b * 512;
  const float h0 = hr[tid], h1 = hr[tid + 256];
  const float s0 = sg[tid], s1 = sg[tid + 256];
  float d = h0 * s0 + h1 * s1;
  float hh = h0 * h0 + h1 * h1;
  float ssq = s0 * s0 + s1 * s1;
  __shared__ float red[3][4];
  d = wave_reduce_sum(d);
  hh = wave_reduce_sum(hh);
  ssq = wave_reduce_sum(ssq);
  if ((tid & 63) == 0) {
    red[0][tid >> 6] = d; red[1][tid >> 6] = hh; red[2][tid >> 6] = ssq;
  }
  __syncthreads();
  if (tid == 0) {
    const float D = red[0][0] + red[0][1] + red[0][2] + red[0][3];
    const float H = red[1][0] + red[1][1] + red[1][2] + red[1][3];
    const float S = red[2][0] + red[2][1] + red[2][2] + red[2][3];
    out[b] = D / (fmaxf(sqrtf(H), 1e-12f) * fmaxf(sqrtf(S), 1e-12f));
  }
}

extern "C" void kernel_launch(void* const* d_in, const int* in_sizes, int n_in,
                              void* d_out, int out_size, void* d_ws, size_t ws_size,
                              hipStream_t stream) {
  const int* query = (const int*)d_in[0];
  const int* support = (const int*)d_in[1];
  const int* qlc = (const int*)d_in[2];
  const int* qrc = (const int*)d_in[4];
  const int* slc = (const int*)d_in[6];
  const int* src_ = (const int*)d_in[8];
  const float* emb = (const float*)d_in[10];
  const float* gcn_w = (const float*)d_in[11];
  const float* gcn_wb = (const float*)d_in[12];
  const float* gcn_b = (const float*)d_in[13];
  const float* p1_w = (const float*)d_in[14];
  const float* p1_b = (const float*)d_in[15];
  const float* p2_w = (const float*)d_in[16];
  const float* p2_b = (const float*)d_in[17];
  const float* ln_g = (const float*)d_in[18];
  const float* ln_b = (const float*)d_in[19];
  const float* w_ih = (const float*)d_in[20];
  const float* w_hh = (const float*)d_in[21];
  const float* b_ih = (const float*)d_in[22];
  const float* b_hh = (const float*)d_in[23];
  float* out = (float*)d_out;

  const int B = in_sizes[0] / 2;   // 2048
  const int F = in_sizes[1] / 2;   // 5
  const int NR = 2 * B + 2 * F;    // 4106

  char* Wb = (char*)d_ws;
  size_t off = 0;
  auto alloc = [&](size_t bytes) {
    size_t o = off;
    off += (bytes + 255) & ~(size_t)255;
    return o;
  };
  const size_t base_o = alloc((size_t)B * 4096 * 4);
  const size_t mc_o   = alloc((size_t)NR * 512 * 2);
  const size_t qn_o   = alloc((size_t)B * 512 * 4);
  const size_t qnb_o  = alloc((size_t)B * 512 * 2);
  const size_t hqb_o  = alloc((size_t)B * 1024 * 2);
  const size_t oq_o   = alloc((size_t)B * 512 * 4);
  const size_t qg_o   = alloc((size_t)B * 512 * 4);
  const size_t qgb_o  = alloc((size_t)B * 512 * 2);
  const size_t cbuf_o = alloc((size_t)B * 1024 * 4);
  const size_t h_o    = alloc((size_t)B * 512 * 4);
  const size_t hb0_o  = alloc((size_t)B * 512 * 2);
  const size_t hb1_o  = alloc((size_t)B * 512 * 2);
  const size_t wihb_o = alloc((size_t)4096 * 512 * 2);
  const size_t whhb_o = alloc((size_t)4096 * 512 * 2);
  const size_t p1b_o  = alloc((size_t)1024 * 512 * 2);
  const size_t p2b_o  = alloc((size_t)512 * 1024 * 2);
  const size_t gcnb_o = alloc((size_t)256 * 512 * 2);
  const size_t bcomb_o= alloc(4096 * 4);
  const size_t sn_o   = alloc((size_t)F * 512 * 4);
  const size_t hs_o   = alloc((size_t)F * 1024 * 4);
  const size_t oss_o  = alloc((size_t)F * 512 * 4);
  const size_t ssb_o  = alloc((size_t)F * 512 * 4);
  const size_t sg_o   = alloc(512 * 4);
  const size_t cvec_o = alloc(4096 * 4);
  // total ~= 87 MB

  auto F32 = [&](size_t o) { return (float*)(Wb + o); };
  auto BF = [&](size_t o) { return (unsigned short*)(Wb + o); };

  // 0. all weight converts + gate-permute + combined bias (one launch)
  convert_all_kernel<<<5252, 256, 0, stream>>>(
      w_ih, w_hh, p1_w, p2_w, gcn_w, b_ih, b_hh, BF(wihb_o), BF(whhb_o),
      BF(p1b_o), BF(p2b_o), BF(gcnb_o), F32(bcomb_o));

  // 1. neighbor encoder -> mc (NR x 512, bf16)
  neighbor_kernel<<<NR, 256, 0, stream>>>(query, support, qlc, qrc, slc, src_,
                                          emb, BF(mc_o), B, F);
  // 2. GCN + remap fused: tanh(mc @ gcn_w^T + b) scattered to qn/qnb/sn
  {
    dim3 g(256 / 64, (NR + 63) / 64);
    gemm64_kernel<<<g, 256, 0, stream>>>(BF(mc_o), 512, BF(gcnb_o), 512,
                                         F32(qn_o), BF(qnb_o), NR, 256, 512,
                                         gcn_wb, gcn_b, nullptr, 1, B, F,
                                         F32(sn_o));
  }
  // 3-4. support_encoder(queries): bf16 MFMA, 64-tile
  {
    dim3 g(1024 / 64, B / 64);
    gemm64_kernel<<<g, 256, 0, stream>>>(BF(qnb_o), 512, BF(p1b_o), 512,
                                         nullptr, BF(hqb_o), B, 1024, 512,
                                         p1_b, nullptr, nullptr, 2, 0, 0,
                                         nullptr);
  }
  {
    dim3 g(512 / 64, B / 64);
    gemm64_kernel<<<g, 256, 0, stream>>>(BF(hqb_o), 1024, BF(p2b_o), 1024,
                                         F32(oq_o), nullptr, B, 512, 1024,
                                         p2_b, nullptr, F32(qn_o), 0, 0, 0,
                                         nullptr);
  }
  // 5-6. support_encoder(supports): fp32 (M=5)
  {
    dim3 g(1024 / 64, 1);
    gemm_nt_kernel<<<g, 256, 0, stream>>>(F32(sn_o), 512, p1_w, 512, F32(hs_o),
                                          F, 1024, 512, p1_b, nullptr, nullptr,
                                          2);
  }
  {
    dim3 g(512 / 64, 1);
    gemm_nt_kernel<<<g, 256, 0, stream>>>(F32(hs_o), 1024, p2_w, 1024,
                                          F32(oss_o), F, 512, 1024, p2_b,
                                          nullptr, F32(sn_o), 0);
  }
  // 7. LN supports + mean -> sg
  ln_kernel<<<F, 256, 0, stream>>>(F32(oss_o), F32(ssb_o), nullptr, ln_g, ln_b);
  smean_kernel<<<2, 256, 0, stream>>>(F32(ssb_o), F32(sg_o), F);
  // 8. LN queries -> qg f32 + bf16
  ln_kernel<<<B, 256, 0, stream>>>(F32(oq_o), F32(qg_o), BF(qgb_o), ln_g, ln_b);
  // 9. cvec (gate-permuted)
  cvec_kernel<<<1024, 256, 0, stream>>>(w_hh, F32(sg_o), F32(cvec_o));
  // 10. base GEMM + fused cell step 0 (c_old = 0); writes base, c, h, hb0
  {
    dim3 g(4096 / 128, B / 128);
    gemm128_kernel<<<g, 256, 0, stream>>>(
        BF(qgb_o), 512, BF(wihb_o), 512, F32(base_o), nullptr, B, 4096, 512,
        F32(bcomb_o), nullptr, nullptr, 0, 1, F32(cbuf_o), F32(qg_o), F32(h_o),
        BF(hb0_o));
  }
  // 11-13. steps 1..3: gates GEMM + fused cell; hb double-buffered
  for (int s = 1; s < 4; ++s) {
    const size_t in_o = (s & 1) ? hb0_o : hb1_o;
    const size_t out_o = (s & 1) ? hb1_o : hb0_o;
    dim3 g(4096 / 128, B / 128);
    gemm128_kernel<<<g, 256, 0, stream>>>(
        BF(in_o), 512, BF(whhb_o), 512, nullptr, nullptr, B, 4096, 512,
        F32(cvec_o), nullptr, F32(base_o), 0, 2, F32(cbuf_o), F32(qg_o),
        F32(h_o), BF(out_o));
  }
  // 14. output
  final_kernel<<<B, 256, 0, stream>>>(F32(h_o), F32(sg_o), out);
}

// Round 4
// 771.389 us; speedup vs baseline: 1.8954x; 1.0434x over previous
//
#include <hip/hip_runtime.h>
#include <math.h>

// ---------------------------------------------------------------------------
// EmbedMatcher: V=200000 D=256 B=2048 F=5 N=64 K=32 DM=512 HID=1024 STEPS=4
// Simplifications (verified vs reference):
//  * GCN mean commutes with linear layer
//  * attn = softmax over ONE column == 1 -> r == support_g (constant)
//  * gates = base + h @ Whh[:, :512]^T + cvec; base/cvec step-invariant
//  * step 0: h_r = 0 -> gates == base
// Round 4: neighbor drops LDS ent-cache (occupancy 41%->~80%, was the
// latency-bound limiter); fast v_exp/v_rcp sigmoid+tanh in cell & GCN
// epilogues (libm expf/tanhf were ~half the gemm128 cycles).
// ---------------------------------------------------------------------------

typedef __attribute__((ext_vector_type(8))) short short8;
typedef __attribute__((ext_vector_type(4))) float floatx4;

__device__ inline unsigned short f2bf(float f) {
  union { float f; unsigned int u; } x;
  x.f = f;
  unsigned int r = x.u + 0x7fffu + ((x.u >> 16) & 1u);  // RNE
  return (unsigned short)(r >> 16);
}
__device__ inline float frcp(float x) { return __builtin_amdgcn_rcpf(x); }
__device__ inline float sigm_f(float x) { return frcp(1.f + __expf(-x)); }
__device__ inline float tanh_f(float x) {
  return 1.f - 2.f * frcp(1.f + __expf(2.f * x));
}

__device__ inline float wave_reduce_sum(float v) {
#pragma unroll
  for (int off = 32; off > 0; off >>= 1) v += __shfl_down(v, off, 64);
  return v;
}

// ---------------- fused weight convert + permute (one launch) --------------
// pack boundaries (float4 units): w_ih 524288 | w_hh 524288 | p1 131072 |
// p2 131072 | gcn 32768 | bias 1024  -> total 1344512 packs, grid 5252.
__global__ __launch_bounds__(256) void convert_all_kernel(
    const float* __restrict__ w_ih, const float* __restrict__ w_hh,
    const float* __restrict__ p1_w, const float* __restrict__ p2_w,
    const float* __restrict__ gcn_w, const float* __restrict__ b_ih,
    const float* __restrict__ b_hh, unsigned short* __restrict__ wihb,
    unsigned short* __restrict__ whhb, unsigned short* __restrict__ p1b,
    unsigned short* __restrict__ p2b, unsigned short* __restrict__ gcnb,
    float* __restrict__ bcomb) {
  const int p = blockIdx.x * 256 + threadIdx.x;
  if (p < 524288) {
    const int e = p * 4, r = e >> 9, c = e & 511;
    const int orig = ((r >> 4) & 3) * 1024 + ((r >> 6) << 4) + (r & 15);
    float4 v = *(const float4*)(w_ih + (size_t)orig * 512 + c);
    *(ushort4*)(wihb + (size_t)r * 512 + c) =
        make_ushort4(f2bf(v.x), f2bf(v.y), f2bf(v.z), f2bf(v.w));
  } else if (p < 1048576) {
    const int e = (p - 524288) * 4, r = e >> 9, c = e & 511;
    const int orig = ((r >> 4) & 3) * 1024 + ((r >> 6) << 4) + (r & 15);
    float4 v = *(const float4*)(w_hh + (size_t)orig * 1024 + c);
    *(ushort4*)(whhb + (size_t)r * 512 + c) =
        make_ushort4(f2bf(v.x), f2bf(v.y), f2bf(v.z), f2bf(v.w));
  } else if (p < 1179648) {
    const int e = (p - 1048576) * 4;
    float4 v = *(const float4*)(p1_w + e);
    *(ushort4*)(p1b + e) =
        make_ushort4(f2bf(v.x), f2bf(v.y), f2bf(v.z), f2bf(v.w));
  } else if (p < 1310720) {
    const int e = (p - 1179648) * 4;
    float4 v = *(const float4*)(p2_w + e);
    *(ushort4*)(p2b + e) =
        make_ushort4(f2bf(v.x), f2bf(v.y), f2bf(v.z), f2bf(v.w));
  } else if (p < 1343488) {
    const int e = (p - 1310720) * 4;
    float4 v = *(const float4*)(gcn_w + e);
    *(ushort4*)(gcnb + e) =
        make_ushort4(f2bf(v.x), f2bf(v.y), f2bf(v.z), f2bf(v.w));
  } else if (p < 1344512) {
    const int c = (p - 1343488) * 4;
    const int orig = ((c >> 4) & 3) * 1024 + ((c >> 6) << 4) + (c & 15);
    float4 a = *(const float4*)(b_ih + orig);
    float4 b = *(const float4*)(b_hh + orig);
    *(float4*)(bcomb + c) =
        make_float4(a.x + b.x, a.y + b.y, a.z + b.z, a.w + b.w);
  }
}

// ---------------- neighbor encoder v3: small LDS, high occupancy -----------
__global__ __launch_bounds__(256) void neighbor_kernel(
    const int* __restrict__ query, const int* __restrict__ support,
    const int* __restrict__ qlc, const int* __restrict__ qrc,
    const int* __restrict__ slc, const int* __restrict__ src_,
    const float* __restrict__ emb, unsigned short* __restrict__ mc,
    int B, int F) {
  const int r = blockIdx.x;
  const int tid = threadIdx.x;
  const int* conn;
  int id;
  if (r < B) {
    conn = qlc + (size_t)r * 128; id = query[2 * r];
  } else if (r < 2 * B) {
    int b = r - B; conn = qrc + (size_t)b * 128; id = query[2 * b + 1];
  } else if (r < 2 * B + F) {
    int f = r - 2 * B; conn = slc + (size_t)f * 128; id = support[2 * f];
  } else {
    int f = r - 2 * B - F; conn = src_ + (size_t)f * 128; id = support[2 * f + 1];
  }

  __shared__ __align__(16) float cent[256];
  __shared__ float sims[64];
  __shared__ int rel_ids[64];
  __shared__ int ent_ids[64];
  __shared__ short list[32];
  __shared__ float red[4];
  __shared__ float cnorm_s;

  if (tid < 64) {
    rel_ids[tid] = conn[2 * tid];
    ent_ids[tid] = conn[2 * tid + 1];
  }
  float cv = emb[(size_t)id * 256 + tid];
  cent[tid] = cv;
  float sq = wave_reduce_sum(cv * cv);
  if ((tid & 63) == 0) red[tid >> 6] = sq;
  __syncthreads();
  if (tid == 0) cnorm_s = sqrtf(red[0] + red[1] + red[2] + red[3]);
  __syncthreads();
  const float cn = cnorm_s;

  const int wave = tid >> 6, lane = tid & 63;
  const float4 cv4 = *(const float4*)(cent + lane * 4);
#pragma unroll 4
  for (int n = wave; n < 64; n += 4) {
    const float* er = emb + (size_t)ent_ids[n] * 256;
    float4 e = *(const float4*)(er + lane * 4);
    float d = e.x * cv4.x + e.y * cv4.y + e.z * cv4.z + e.w * cv4.w;
    float s2 = e.x * e.x + e.y * e.y + e.z * e.z + e.w * e.w;
#pragma unroll
    for (int off = 32; off > 0; off >>= 1) {
      d += __shfl_down(d, off, 64);
      s2 += __shfl_down(s2, off, 64);
    }
    if (lane == 0) sims[n] = d / fmaxf(cn * sqrtf(s2), 1e-8f);
  }
  __syncthreads();

  // top-K=32, stable tie-break (lower index first) == lax.top_k; ranks unique
  if (tid < 64) {
    float my = sims[tid];
    int rank = 0;
#pragma unroll 8
    for (int j = 0; j < 64; ++j) {
      float sj = sims[j];
      rank += (sj > my) || (sj == my && j < tid);
    }
    if (rank < 32) list[rank] = (short)tid;
  }
  __syncthreads();

  float accR = 0.f, accE = 0.f;
#pragma unroll 2
  for (int k = 0; k < 32; k += 4) {
    const int n0 = list[k], n1 = list[k + 1], n2 = list[k + 2], n3 = list[k + 3];
    const float* pr0 = emb + (size_t)rel_ids[n0] * 256;
    const float* pr1 = emb + (size_t)rel_ids[n1] * 256;
    const float* pr2 = emb + (size_t)rel_ids[n2] * 256;
    const float* pr3 = emb + (size_t)rel_ids[n3] * 256;
    const float* pe0 = emb + (size_t)ent_ids[n0] * 256;
    const float* pe1 = emb + (size_t)ent_ids[n1] * 256;
    const float* pe2 = emb + (size_t)ent_ids[n2] * 256;
    const float* pe3 = emb + (size_t)ent_ids[n3] * 256;
    const float r0 = pr0[tid], r1 = pr1[tid], r2 = pr2[tid], r3 = pr3[tid];
    const float e0 = pe0[tid], e1 = pe1[tid], e2 = pe2[tid], e3 = pe3[tid];
    accR += (r0 + r1) + (r2 + r3);
    accE += (e0 + e1) + (e2 + e3);
  }
  mc[(size_t)r * 512 + tid] = f2bf(accR * (1.f / 32.f));
  mc[(size_t)r * 512 + 256 + tid] = f2bf(accE * (1.f / 32.f));
}

// ------------- bf16 MFMA GEMM_NT 128x128; modes: 0 normal, 1 base+cell0,
// ------------- 2 step+cell.  N%128==0, K%32==0, M row-guarded.
#define LDSW 40
__global__ __launch_bounds__(256) void gemm128_kernel(
    const unsigned short* __restrict__ A, int lda,
    const unsigned short* __restrict__ Bm, int ldb,
    float* __restrict__ C, unsigned short* __restrict__ Cbf,
    int M, int N, int K,
    const float* __restrict__ bias1, const float* __restrict__ bias2,
    const float* __restrict__ addmat, int act, int mode,
    float* __restrict__ cbuf, const float* __restrict__ qg,
    float* __restrict__ h, unsigned short* __restrict__ hbf) {
  __shared__ __align__(16) unsigned short As[128 * LDSW];
  __shared__ __align__(16) unsigned short Bs[128 * LDSW];
  const int tid = threadIdx.x;
  const int wid = tid >> 6, lane = tid & 63;
  const int quad = lane >> 4, l16 = lane & 15;
  const int wr = (wid >> 1) * 64, wc = (wid & 1) * 64;
  const int row0 = blockIdx.y * 128, col0 = blockIdx.x * 128;

  const int lr = tid >> 1, lc = (tid & 1) * 16;
  const bool arow_ok = (row0 + lr) < M;
  const unsigned short* Ap = A + (size_t)(row0 + lr) * lda + lc;
  const unsigned short* Bp = Bm + (size_t)(col0 + lr) * ldb + lc;

  floatx4 acc[4][4];
#pragma unroll
  for (int i = 0; i < 4; ++i)
#pragma unroll
    for (int j = 0; j < 4; ++j) {
      floatx4 z = {0.f, 0.f, 0.f, 0.f};
      acc[i][j] = z;
    }

  for (int k0 = 0; k0 < K; k0 += 32) {
    uint4 a0 = make_uint4(0, 0, 0, 0), a1 = make_uint4(0, 0, 0, 0);
    if (arow_ok) {
      a0 = *(const uint4*)(Ap + k0);
      a1 = *(const uint4*)(Ap + k0 + 8);
    }
    uint4 b0 = *(const uint4*)(Bp + k0);
    uint4 b1 = *(const uint4*)(Bp + k0 + 8);
    *(uint4*)&As[lr * LDSW + lc] = a0;
    *(uint4*)&As[lr * LDSW + lc + 8] = a1;
    *(uint4*)&Bs[lr * LDSW + lc] = b0;
    *(uint4*)&Bs[lr * LDSW + lc + 8] = b1;
    __syncthreads();

    short8 af[4], bfr[4];
#pragma unroll
    for (int i = 0; i < 4; ++i)
      af[i] = *(const short8*)&As[(wr + i * 16 + l16) * LDSW + quad * 8];
#pragma unroll
    for (int j = 0; j < 4; ++j)
      bfr[j] = *(const short8*)&Bs[(wc + j * 16 + l16) * LDSW + quad * 8];
#pragma unroll
    for (int i = 0; i < 4; ++i)
#pragma unroll
      for (int j = 0; j < 4; ++j)
        acc[i][j] = __builtin_amdgcn_mfma_f32_16x16x32_bf16(af[i], bfr[j],
                                                            acc[i][j], 0, 0, 0);
    __syncthreads();
  }

#pragma unroll
  for (int i = 0; i < 4; ++i) {
#pragma unroll
    for (int r = 0; r < 4; ++r) {
      const int row = row0 + wr + i * 16 + quad * 4 + r;
      if (row >= M) continue;
      float vals[4];
#pragma unroll
      for (int j = 0; j < 4; ++j) {
        const int col = col0 + wc + j * 16 + l16;
        float v = acc[i][j][r];
        if (bias1) v += bias1[col];
        if (bias2) v += bias2[col];
        if (addmat) v += addmat[(size_t)row * N + col];
        vals[j] = v;
      }
      if (mode == 0) {
#pragma unroll
        for (int j = 0; j < 4; ++j) {
          const int col = col0 + wc + j * 16 + l16;
          float v = vals[j];
          if (act == 1) v = tanh_f(v);
          else if (act == 2) v = fmaxf(v, 0.f);
          if (C) C[(size_t)row * N + col] = v;
          if (Cbf) Cbf[(size_t)row * N + col] = f2bf(v);
        }
      } else {
        if (mode == 1) {
#pragma unroll
          for (int j = 0; j < 4; ++j)
            C[(size_t)row * N + (col0 + wc + j * 16 + l16)] = vals[j];
        }
        // j == gate (i,f,g,o) of gate-index n, by weight-row permutation
        const int n = (((col0 + wc) >> 6) << 4) + l16;
        const float cold = (mode == 1) ? 0.f : cbuf[(size_t)row * 1024 + n];
        const float cn =
            sigm_f(vals[1]) * cold + sigm_f(vals[0]) * tanh_f(vals[2]);
        cbuf[(size_t)row * 1024 + n] = cn;
        if (n < 512) {
          const float hv =
              qg[(size_t)row * 512 + n] + sigm_f(vals[3]) * tanh_f(cn);
          h[(size_t)row * 512 + n] = hv;
          hbf[(size_t)row * 512 + n] = f2bf(hv);
        }
      }
    }
  }
}

// ------------- bf16 MFMA GEMM_NT 64x64 (high-occupancy small GEMMs) --------
// snptr != null => GCN remap epilogue (scatter rows to qn/qnb/sn).
__global__ __launch_bounds__(256) void gemm64_kernel(
    const unsigned short* __restrict__ A, int lda,
    const unsigned short* __restrict__ Bm, int ldb,
    float* __restrict__ C, unsigned short* __restrict__ Cbf,
    int M, int N, int K,
    const float* __restrict__ bias1, const float* __restrict__ bias2,
    const float* __restrict__ addmat, int act, int rB, int rF,
    float* __restrict__ snptr) {
  __shared__ __align__(16) unsigned short As[64 * LDSW];
  __shared__ __align__(16) unsigned short Bs[64 * LDSW];
  const int tid = threadIdx.x;
  const int wid = tid >> 6, lane = tid & 63;
  const int quad = lane >> 4, l16 = lane & 15;
  const int wr = (wid >> 1) * 32, wc = (wid & 1) * 32;
  const int row0 = blockIdx.y * 64, col0 = blockIdx.x * 64;

  const int t = tid & 127;
  const int lr = t >> 1, lc = (t & 1) * 16;
  const bool isA = tid < 128;
  const bool row_ok = isA ? (row0 + lr) < M : true;
  const unsigned short* P = isA ? (A + (size_t)(row0 + lr) * lda + lc)
                                : (Bm + (size_t)(col0 + lr) * ldb + lc);
  unsigned short* S = (isA ? As : Bs) + lr * LDSW + lc;

  floatx4 acc[2][2];
#pragma unroll
  for (int i = 0; i < 2; ++i)
#pragma unroll
    for (int j = 0; j < 2; ++j) {
      floatx4 z = {0.f, 0.f, 0.f, 0.f};
      acc[i][j] = z;
    }

  for (int k0 = 0; k0 < K; k0 += 32) {
    uint4 v0 = make_uint4(0, 0, 0, 0), v1 = make_uint4(0, 0, 0, 0);
    if (row_ok) {
      v0 = *(const uint4*)(P + k0);
      v1 = *(const uint4*)(P + k0 + 8);
    }
    *(uint4*)S = v0;
    *(uint4*)(S + 8) = v1;
    __syncthreads();

    short8 af[2], bfr[2];
#pragma unroll
    for (int i = 0; i < 2; ++i)
      af[i] = *(const short8*)&As[(wr + i * 16 + l16) * LDSW + quad * 8];
#pragma unroll
    for (int j = 0; j < 2; ++j)
      bfr[j] = *(const short8*)&Bs[(wc + j * 16 + l16) * LDSW + quad * 8];
#pragma unroll
    for (int i = 0; i < 2; ++i)
#pragma unroll
      for (int j = 0; j < 2; ++j)
        acc[i][j] = __builtin_amdgcn_mfma_f32_16x16x32_bf16(af[i], bfr[j],
                                                            acc[i][j], 0, 0, 0);
    __syncthreads();
  }

#pragma unroll
  for (int i = 0; i < 2; ++i) {
#pragma unroll
    for (int r = 0; r < 4; ++r) {
      const int row = row0 + wr + i * 16 + quad * 4 + r;
      if (row >= M) continue;
#pragma unroll
      for (int j = 0; j < 2; ++j) {
        const int col = col0 + wc + j * 16 + l16;
        float v = acc[i][j][r];
        if (bias1) v += bias1[col];
        if (bias2) v += bias2[col];
        if (addmat) v += addmat[(size_t)row * N + col];
        if (act == 1) v = tanh_f(v);
        else if (act == 2) v = fmaxf(v, 0.f);
        if (snptr) {  // GCN remap: row -> {qn | qn+256 | sn | sn+256}
          if (row < rB) {
            C[(size_t)row * 512 + col] = v;
            Cbf[(size_t)row * 512 + col] = f2bf(v);
          } else if (row < 2 * rB) {
            C[(size_t)(row - rB) * 512 + 256 + col] = v;
            Cbf[(size_t)(row - rB) * 512 + 256 + col] = f2bf(v);
          } else if (row < 2 * rB + rF) {
            snptr[(size_t)(row - 2 * rB) * 512 + col] = v;
          } else {
            snptr[(size_t)(row - 2 * rB - rF) * 512 + 256 + col] = v;
          }
        } else {
          if (C) C[(size_t)row * N + col] = v;
          if (Cbf) Cbf[(size_t)row * N + col] = f2bf(v);
        }
      }
    }
  }
}

// ------------- fp32 GEMM_NT (tiny M=F support path) ------------------------
__global__ __launch_bounds__(256) void gemm_nt_kernel(
    const float* __restrict__ A, int lda, const float* __restrict__ B, int ldb,
    float* __restrict__ C, int M, int N, int K,
    const float* __restrict__ bias1, const float* __restrict__ bias2,
    const float* __restrict__ addmat, int act) {
  __shared__ float As[16][65];
  __shared__ float Bs[16][65];
  const int tid = threadIdx.x;
  const int col0 = blockIdx.x * 64;
  const int row0 = blockIdx.y * 64;
  const int tx = tid & 15, ty = tid >> 4;
  const int lr = tid >> 2, lk = (tid & 3) << 2;

  float acc[4][4];
#pragma unroll
  for (int i = 0; i < 4; ++i)
#pragma unroll
    for (int j = 0; j < 4; ++j) acc[i][j] = 0.f;

  const int ar = row0 + lr;
  const bool avalid = ar < M;
  const float* Aptr = A + (size_t)ar * lda + lk;
  const float* Bptr = B + (size_t)(col0 + lr) * ldb + lk;

  for (int k0 = 0; k0 < K; k0 += 16) {
    float4 av = make_float4(0.f, 0.f, 0.f, 0.f);
    if (avalid) av = *(const float4*)(Aptr + k0);
    float4 bv = *(const float4*)(Bptr + k0);
    As[lk + 0][lr] = av.x; As[lk + 1][lr] = av.y;
    As[lk + 2][lr] = av.z; As[lk + 3][lr] = av.w;
    Bs[lk + 0][lr] = bv.x; Bs[lk + 1][lr] = bv.y;
    Bs[lk + 2][lr] = bv.z; Bs[lk + 3][lr] = bv.w;
    __syncthreads();
#pragma unroll
    for (int k = 0; k < 16; ++k) {
      float a0 = As[k][ty * 4 + 0], a1 = As[k][ty * 4 + 1];
      float a2 = As[k][ty * 4 + 2], a3 = As[k][ty * 4 + 3];
      float b0 = Bs[k][tx * 4 + 0], b1 = Bs[k][tx * 4 + 1];
      float b2 = Bs[k][tx * 4 + 2], b3 = Bs[k][tx * 4 + 3];
      acc[0][0] += a0 * b0; acc[0][1] += a0 * b1; acc[0][2] += a0 * b2; acc[0][3] += a0 * b3;
      acc[1][0] += a1 * b0; acc[1][1] += a1 * b1; acc[1][2] += a1 * b2; acc[1][3] += a1 * b3;
      acc[2][0] += a2 * b0; acc[2][1] += a2 * b1; acc[2][2] += a2 * b2; acc[2][3] += a2 * b3;
      acc[3][0] += a3 * b0; acc[3][1] += a3 * b1; acc[3][2] += a3 * b2; acc[3][3] += a3 * b3;
    }
    __syncthreads();
  }

#pragma unroll
  for (int i = 0; i < 4; ++i) {
    const int r = row0 + ty * 4 + i;
    if (r >= M) continue;
#pragma unroll
    for (int j = 0; j < 4; ++j) {
      const int c = col0 + tx * 4 + j;
      float v = acc[i][j];
      if (bias1) v += bias1[c];
      if (bias2) v += bias2[c];
      if (addmat) v += addmat[(size_t)r * N + c];
      if (act == 1) v = tanhf(v);
      else if (act == 2) v = fmaxf(v, 0.f);
      C[(size_t)r * N + c] = v;
    }
  }
}

// ------------- LayerNorm rows of 512; optional bf16 copy -------------------
__global__ __launch_bounds__(256) void ln_kernel(
    const float* __restrict__ X, float* __restrict__ Y,
    unsigned short* __restrict__ Ybf,
    const float* __restrict__ g, const float* __restrict__ bta) {
  const int r = blockIdx.x;
  const int tid = threadIdx.x;
  const float* x = X + (size_t)r * 512;
  float x0 = x[tid], x1 = x[tid + 256];
  __shared__ float red[4];
  float s = wave_reduce_sum(x0 + x1);
  if ((tid & 63) == 0) red[tid >> 6] = s;
  __syncthreads();
  const float mean = (red[0] + red[1] + red[2] + red[3]) * (1.f / 512.f);
  __syncthreads();
  const float d0 = x0 - mean, d1 = x1 - mean;
  float v = wave_reduce_sum(d0 * d0 + d1 * d1);
  if ((tid & 63) == 0) red[tid >> 6] = v;
  __syncthreads();
  const float var = (red[0] + red[1] + red[2] + red[3]) * (1.f / 512.f);
  const float inv = 1.f / sqrtf(var + 1e-5f);
  const float y0 = d0 * inv * g[tid] + bta[tid];
  const float y1 = d1 * inv * g[tid + 256] + bta[tid + 256];
  float* y = Y + (size_t)r * 512;
  y[tid] = y0;
  y[tid + 256] = y1;
  if (Ybf) {
    Ybf[(size_t)r * 512 + tid] = f2bf(y0);
    Ybf[(size_t)r * 512 + tid + 256] = f2bf(y1);
  }
}

// ------------- mean over F support rows -> sg (512) ------------------------
__global__ void smean_kernel(const float* __restrict__ ss,
                             float* __restrict__ sg, int F) {
  const int d = blockIdx.x * blockDim.x + threadIdx.x;
  if (d < 512) {
    float s = 0.f;
    for (int f = 0; f < F; ++f) s += ss[(size_t)f * 512 + d];
    sg[d] = s / (float)F;
  }
}

// ------------- cvec[jp] = sum_d sg[d] * w_hh[orig(jp), 512+d] (permuted) ---
__global__ __launch_bounds__(256) void cvec_kernel(
    const float* __restrict__ whh, const float* __restrict__ sg,
    float* __restrict__ cv) {
  const int wave = threadIdx.x >> 6, lane = threadIdx.x & 63;
  const int jp = blockIdx.x * 4 + wave;
  const int orig = ((jp >> 4) & 3) * 1024 + ((jp >> 6) << 4) + (jp & 15);
  const float* wr = whh + (size_t)orig * 1024 + 512;
  float s = 0.f;
#pragma unroll
  for (int d = lane; d < 512; d += 64) s += wr[d] * sg[d];
  s = wave_reduce_sum(s);
  if (lane == 0) cv[jp] = s;
}

// ------------- out[b] = cosine(h[b], sg) -----------------------------------
__global__ __launch_bounds__(256) void final_kernel(
    const float* __restrict__ h, const float* __restrict__ sg,
    float* __restrict__ out) {
  const int b = blockIdx.x, tid = threadIdx.x;
  const float* hr = h + (size_t)b * 512;
  const float h0 = hr[tid], h1 = hr[tid + 256];
  const float s0 = sg[tid], s1 = sg[tid + 256];
  float d = h0 * s0 + h1 * s1;
  float hh = h0 * h0 + h1 * h1;
  float ssq = s0 * s0 + s1 * s1;
  __shared__ float red[3][4];
  d = wave_reduce_sum(d);
  hh = wave_reduce_sum(hh);
  ssq = wave_reduce_sum(ssq);
  if ((tid & 63) == 0) {
    red[0][tid >> 6] = d; red[1][tid >> 6] = hh; red[2][tid >> 6] = ssq;
  }
  __syncthreads();
  if (tid == 0) {
    const float D = red[0][0] + red[0][1] + red[0][2] + red[0][3];
    const float H = red[1][0] + red[1][1] + red[1][2] + red[1][3];
    const float S = red[2][0] + red[2][1] + red[2][2] + red[2][3];
    out[b] = D / (fmaxf(sqrtf(H), 1e-12f) * fmaxf(sqrtf(S), 1e-12f));
  }
}

extern "C" void kernel_launch(void* const* d_in, const int* in_sizes, int n_in,
                              void* d_out, int out_size, void* d_ws, size_t ws_size,
                              hipStream_t stream) {
  const int* query = (const int*)d_in[0];
  const int* support = (const int*)d_in[1];
  const int* qlc = (const int*)d_in[2];
  const int* qrc = (const int*)d_in[4];
  const int* slc = (const int*)d_in[6];
  const int* src_ = (const int*)d_in[8];
  const float* emb = (const float*)d_in[10];
  const float* gcn_w = (const float*)d_in[11];
  const float* gcn_wb = (const float*)d_in[12];
  const float* gcn_b = (const float*)d_in[13];
  const float* p1_w = (const float*)d_in[14];
  const float* p1_b = (const float*)d_in[15];
  const float* p2_w = (const float*)d_in[16];
  const float* p2_b = (const float*)d_in[17];
  const float* ln_g = (const float*)d_in[18];
  const float* ln_b = (const float*)d_in[19];
  const float* w_ih = (const float*)d_in[20];
  const float* w_hh = (const float*)d_in[21];
  const float* b_ih = (const float*)d_in[22];
  const float* b_hh = (const float*)d_in[23];
  float* out = (float*)d_out;

  const int B = in_sizes[0] / 2;   // 2048
  const int F = in_sizes[1] / 2;   // 5
  const int NR = 2 * B + 2 * F;    // 4106

  char* Wb = (char*)d_ws;
  size_t off = 0;
  auto alloc = [&](size_t bytes) {
    size_t o = off;
    off += (bytes + 255) & ~(size_t)255;
    return o;
  };
  const size_t base_o = alloc((size_t)B * 4096 * 4);
  const size_t mc_o   = alloc((size_t)NR * 512 * 2);
  const size_t qn_o   = alloc((size_t)B * 512 * 4);
  const size_t qnb_o  = alloc((size_t)B * 512 * 2);
  const size_t hqb_o  = alloc((size_t)B * 1024 * 2);
  const size_t oq_o   = alloc((size_t)B * 512 * 4);
  const size_t qg_o   = alloc((size_t)B * 512 * 4);
  const size_t qgb_o  = alloc((size_t)B * 512 * 2);
  const size_t cbuf_o = alloc((size_t)B * 1024 * 4);
  const size_t h_o    = alloc((size_t)B * 512 * 4);
  const size_t hb0_o  = alloc((size_t)B * 512 * 2);
  const size_t hb1_o  = alloc((size_t)B * 512 * 2);
  const size_t wihb_o = alloc((size_t)4096 * 512 * 2);
  const size_t whhb_o = alloc((size_t)4096 * 512 * 2);
  const size_t p1b_o  = alloc((size_t)1024 * 512 * 2);
  const size_t p2b_o  = alloc((size_t)512 * 1024 * 2);
  const size_t gcnb_o = alloc((size_t)256 * 512 * 2);
  const size_t bcomb_o= alloc(4096 * 4);
  const size_t sn_o   = alloc((size_t)F * 512 * 4);
  const size_t hs_o   = alloc((size_t)F * 1024 * 4);
  const size_t oss_o  = alloc((size_t)F * 512 * 4);
  const size_t ssb_o  = alloc((size_t)F * 512 * 4);
  const size_t sg_o   = alloc(512 * 4);
  const size_t cvec_o = alloc(4096 * 4);
  // total ~= 87 MB

  auto F32 = [&](size_t o) { return (float*)(Wb + o); };
  auto BF = [&](size_t o) { return (unsigned short*)(Wb + o); };

  // 0. all weight converts + gate-permute + combined bias (one launch)
  convert_all_kernel<<<5252, 256, 0, stream>>>(
      w_ih, w_hh, p1_w, p2_w, gcn_w, b_ih, b_hh, BF(wihb_o), BF(whhb_o),
      BF(p1b_o), BF(p2b_o), BF(gcnb_o), F32(bcomb_o));

  // 1. neighbor encoder -> mc (NR x 512, bf16)
  neighbor_kernel<<<NR, 256, 0, stream>>>(query, support, qlc, qrc, slc, src_,
                                          emb, BF(mc_o), B, F);
  // 2. GCN + remap fused: tanh(mc @ gcn_w^T + b) scattered to qn/qnb/sn
  {
    dim3 g(256 / 64, (NR + 63) / 64);
    gemm64_kernel<<<g, 256, 0, stream>>>(BF(mc_o), 512, BF(gcnb_o), 512,
                                         F32(qn_o), BF(qnb_o), NR, 256, 512,
                                         gcn_wb, gcn_b, nullptr, 1, B, F,
                                         F32(sn_o));
  }
  // 3-4. support_encoder(queries): bf16 MFMA, 64-tile
  {
    dim3 g(1024 / 64, B / 64);
    gemm64_kernel<<<g, 256, 0, stream>>>(BF(qnb_o), 512, BF(p1b_o), 512,
                                         nullptr, BF(hqb_o), B, 1024, 512,
                                         p1_b, nullptr, nullptr, 2, 0, 0,
                                         nullptr);
  }
  {
    dim3 g(512 / 64, B / 64);
    gemm64_kernel<<<g, 256, 0, stream>>>(BF(hqb_o), 1024, BF(p2b_o), 1024,
                                         F32(oq_o), nullptr, B, 512, 1024,
                                         p2_b, nullptr, F32(qn_o), 0, 0, 0,
                                         nullptr);
  }
  // 5-6. support_encoder(supports): fp32 (M=5)
  {
    dim3 g(1024 / 64, 1);
    gemm_nt_kernel<<<g, 256, 0, stream>>>(F32(sn_o), 512, p1_w, 512, F32(hs_o),
                                          F, 1024, 512, p1_b, nullptr, nullptr,
                                          2);
  }
  {
    dim3 g(512 / 64, 1);
    gemm_nt_kernel<<<g, 256, 0, stream>>>(F32(hs_o), 1024, p2_w, 1024,
                                          F32(oss_o), F, 512, 1024, p2_b,
                                          nullptr, F32(sn_o), 0);
  }
  // 7. LN supports + mean -> sg
  ln_kernel<<<F, 256, 0, stream>>>(F32(oss_o), F32(ssb_o), nullptr, ln_g, ln_b);
  smean_kernel<<<2, 256, 0, stream>>>(F32(ssb_o), F32(sg_o), F);
  // 8. LN queries -> qg f32 + bf16
  ln_kernel<<<B, 256, 0, stream>>>(F32(oq_o), F32(qg_o), BF(qgb_o), ln_g, ln_b);
  // 9. cvec (gate-permuted)
  cvec_kernel<<<1024, 256, 0, stream>>>(w_hh, F32(sg_o), F32(cvec_o));
  // 10. base GEMM + fused cell step 0 (c_old = 0); writes base, c, h, hb0
  {
    dim3 g(4096 / 128, B / 128);
    gemm128_kernel<<<g, 256, 0, stream>>>(
        BF(qgb_o), 512, BF(wihb_o), 512, F32(base_o), nullptr, B, 4096, 512,
        F32(bcomb_o), nullptr, nullptr, 0, 1, F32(cbuf_o), F32(qg_o), F32(h_o),
        BF(hb0_o));
  }
  // 11-13. steps 1..3: gates GEMM + fused cell; hb double-buffered
  for (int s = 1; s < 4; ++s) {
    const size_t in_o = (s & 1) ? hb0_o : hb1_o;
    const size_t out_o = (s & 1) ? hb1_o : hb0_o;
    dim3 g(4096 / 128, B / 128);
    gemm128_kernel<<<g, 256, 0, stream>>>(
        BF(in_o), 512, BF(whhb_o), 512, nullptr, nullptr, B, 4096, 512,
        F32(cvec_o), nullptr, F32(base_o), 0, 2, F32(cbuf_o), F32(qg_o),
        F32(h_o), BF(out_o));
  }
  // 14. output
  final_kernel<<<B, 256, 0, stream>>>(F32(h_o), F32(sg_o), out);
}

// Round 5
// 762.431 us; speedup vs baseline: 1.9176x; 1.0117x over previous
//
#include <hip/hip_runtime.h>
#include <math.h>

// ---------------------------------------------------------------------------
// EmbedMatcher: V=200000 D=256 B=2048 F=5 N=64 K=32 DM=512 HID=1024 STEPS=4
// Simplifications (verified vs reference):
//  * GCN mean commutes with linear layer
//  * attn = softmax over ONE column == 1 -> r == support_g (constant)
//  * gates = base + h @ Whh[:, :512]^T + cvec; base/cvec step-invariant
//  * step 0: h_r = 0 -> gates == base
// Round 5: GEMM staging via global_load_lds width=16 (m97 recipe) with
// XOR-swizzled unpadded LDS (physq = quad ^ ((row>>1)&3)) -> optimal bank
// pattern AND wave-uniform-base compatible; neighbor caches ent rows in
// bf16 registers (no 2nd ent gather, no LDS occupancy hit); support LN+mean
// fused to one block.
// ---------------------------------------------------------------------------

typedef __attribute__((ext_vector_type(8))) short short8;
typedef __attribute__((ext_vector_type(4))) float floatx4;

__device__ inline unsigned short f2bf(float f) {
  union { float f; unsigned int u; } x;
  x.f = f;
  unsigned int r = x.u + 0x7fffu + ((x.u >> 16) & 1u);  // RNE
  return (unsigned short)(r >> 16);
}
__device__ inline float bf2f(unsigned short u) {
  union { unsigned int i; float f; } x;
  x.i = ((unsigned int)u) << 16;
  return x.f;
}
__device__ inline float frcp(float x) { return __builtin_amdgcn_rcpf(x); }
__device__ inline float sigm_f(float x) { return frcp(1.f + __expf(-x)); }
__device__ inline float tanh_f(float x) {
  return 1.f - 2.f * frcp(1.f + __expf(2.f * x));
}

// async global->LDS, 16 B per lane; lane i lands at l + i*16 (wave-uniform l)
#if defined(__has_builtin)
#if __has_builtin(__builtin_amdgcn_global_load_lds)
#define HAVE_GLL 1
#endif
#endif
#ifdef HAVE_GLL
__device__ inline void load_lds16(const void* g, void* l) {
  __builtin_amdgcn_global_load_lds(
      (const __attribute__((address_space(1))) unsigned int*)(uintptr_t)g,
      (__attribute__((address_space(3))) unsigned int*)(unsigned int)(uintptr_t)l,
      16, 0, 0);
}
#else
__device__ inline void load_lds16(const void* g, void* l) {
  const int lane = threadIdx.x & 63;
  *(uint4*)((char*)l + lane * 16) = *(const uint4*)g;
}
#endif

__device__ inline float wave_reduce_sum(float v) {
#pragma unroll
  for (int off = 32; off > 0; off >>= 1) v += __shfl_down(v, off, 64);
  return v;
}

// ---------------- fused weight convert + permute (one launch) --------------
__global__ __launch_bounds__(256) void convert_all_kernel(
    const float* __restrict__ w_ih, const float* __restrict__ w_hh,
    const float* __restrict__ p1_w, const float* __restrict__ p2_w,
    const float* __restrict__ gcn_w, const float* __restrict__ b_ih,
    const float* __restrict__ b_hh, unsigned short* __restrict__ wihb,
    unsigned short* __restrict__ whhb, unsigned short* __restrict__ p1b,
    unsigned short* __restrict__ p2b, unsigned short* __restrict__ gcnb,
    float* __restrict__ bcomb) {
  const int p = blockIdx.x * 256 + threadIdx.x;
  if (p < 524288) {
    const int e = p * 4, r = e >> 9, c = e & 511;
    const int orig = ((r >> 4) & 3) * 1024 + ((r >> 6) << 4) + (r & 15);
    float4 v = *(const float4*)(w_ih + (size_t)orig * 512 + c);
    *(ushort4*)(wihb + (size_t)r * 512 + c) =
        make_ushort4(f2bf(v.x), f2bf(v.y), f2bf(v.z), f2bf(v.w));
  } else if (p < 1048576) {
    const int e = (p - 524288) * 4, r = e >> 9, c = e & 511;
    const int orig = ((r >> 4) & 3) * 1024 + ((r >> 6) << 4) + (r & 15);
    float4 v = *(const float4*)(w_hh + (size_t)orig * 1024 + c);
    *(ushort4*)(whhb + (size_t)r * 512 + c) =
        make_ushort4(f2bf(v.x), f2bf(v.y), f2bf(v.z), f2bf(v.w));
  } else if (p < 1179648) {
    const int e = (p - 1048576) * 4;
    float4 v = *(const float4*)(p1_w + e);
    *(ushort4*)(p1b + e) =
        make_ushort4(f2bf(v.x), f2bf(v.y), f2bf(v.z), f2bf(v.w));
  } else if (p < 1310720) {
    const int e = (p - 1179648) * 4;
    float4 v = *(const float4*)(p2_w + e);
    *(ushort4*)(p2b + e) =
        make_ushort4(f2bf(v.x), f2bf(v.y), f2bf(v.z), f2bf(v.w));
  } else if (p < 1343488) {
    const int e = (p - 1310720) * 4;
    float4 v = *(const float4*)(gcn_w + e);
    *(ushort4*)(gcnb + e) =
        make_ushort4(f2bf(v.x), f2bf(v.y), f2bf(v.z), f2bf(v.w));
  } else if (p < 1344512) {
    const int c = (p - 1343488) * 4;
    const int orig = ((c >> 4) & 3) * 1024 + ((c >> 6) << 4) + (c & 15);
    float4 a = *(const float4*)(b_ih + orig);
    float4 b = *(const float4*)(b_hh + orig);
    *(float4*)(bcomb + c) =
        make_float4(a.x + b.x, a.y + b.y, a.z + b.z, a.w + b.w);
  }
}

// ---------------- neighbor encoder v5: reg-cached ent rows -----------------
__global__ __launch_bounds__(256) void neighbor_kernel(
    const int* __restrict__ query, const int* __restrict__ support,
    const int* __restrict__ qlc, const int* __restrict__ qrc,
    const int* __restrict__ slc, const int* __restrict__ src_,
    const float* __restrict__ emb, unsigned short* __restrict__ mc,
    int B, int F) {
  const int r = blockIdx.x;
  const int tid = threadIdx.x;
  const int* conn;
  int id;
  if (r < B) {
    conn = qlc + (size_t)r * 128; id = query[2 * r];
  } else if (r < 2 * B) {
    int b = r - B; conn = qrc + (size_t)b * 128; id = query[2 * b + 1];
  } else if (r < 2 * B + F) {
    int f = r - 2 * B; conn = slc + (size_t)f * 128; id = support[2 * f];
  } else {
    int f = r - 2 * B - F; conn = src_ + (size_t)f * 128; id = support[2 * f + 1];
  }

  __shared__ __align__(16) float cent[256];
  __shared__ __align__(16) float entpart[4 * 256];
  __shared__ float sims[64];
  __shared__ int rel_ids[64];
  __shared__ int ent_ids[64];
  __shared__ short list[32];
  __shared__ float red[4];
  __shared__ float cnorm_s;
  __shared__ unsigned long long selmask_s;

  if (tid < 64) {
    rel_ids[tid] = conn[2 * tid];
    ent_ids[tid] = conn[2 * tid + 1];
  }
  float cv = emb[(size_t)id * 256 + tid];
  cent[tid] = cv;
  float sq = wave_reduce_sum(cv * cv);
  if ((tid & 63) == 0) red[tid >> 6] = sq;
  __syncthreads();
  if (tid == 0) cnorm_s = sqrtf(red[0] + red[1] + red[2] + red[3]);
  __syncthreads();
  const float cn = cnorm_s;

  const int wave = tid >> 6, lane = tid & 63;
  const float4 cv4 = *(const float4*)(cent + lane * 4);
  uint2 ec[16];  // bf16x4-packed cache of this wave's 16 ent rows (lane slice)
#pragma unroll
  for (int t = 0; t < 16; ++t) {
    const int n = wave + 4 * t;
    const float* er = emb + (size_t)ent_ids[n] * 256;
    float4 e = *(const float4*)(er + lane * 4);
    ec[t].x = (unsigned)f2bf(e.x) | ((unsigned)f2bf(e.y) << 16);
    ec[t].y = (unsigned)f2bf(e.z) | ((unsigned)f2bf(e.w) << 16);
    float d = e.x * cv4.x + e.y * cv4.y + e.z * cv4.z + e.w * cv4.w;
    float s2 = e.x * e.x + e.y * e.y + e.z * e.z + e.w * e.w;
#pragma unroll
    for (int off = 32; off > 0; off >>= 1) {
      d += __shfl_down(d, off, 64);
      s2 += __shfl_down(s2, off, 64);
    }
    if (lane == 0) sims[n] = d / fmaxf(cn * sqrtf(s2), 1e-8f);
  }
  __syncthreads();

  // top-K=32, stable tie-break (lower index first) == lax.top_k (wave 0 only)
  if (wave == 0) {
    float my = sims[lane];
    int rank = 0;
#pragma unroll 8
    for (int j = 0; j < 64; ++j) {
      float sj = sims[j];
      rank += (sj > my) || (sj == my && j < lane);
    }
    if (rank < 32) list[rank] = (short)lane;
    unsigned long long m = __ballot(rank < 32);
    if (lane == 0) selmask_s = m;
  }
  __syncthreads();

  // selected-ent partial sums from register cache
  const unsigned long long selm = selmask_s;
  float4 pa = make_float4(0.f, 0.f, 0.f, 0.f);
#pragma unroll
  for (int t = 0; t < 16; ++t) {
    const int n = wave + 4 * t;
    if ((selm >> n) & 1ull) {
      pa.x += bf2f((unsigned short)(ec[t].x & 0xffff));
      pa.y += bf2f((unsigned short)(ec[t].x >> 16));
      pa.z += bf2f((unsigned short)(ec[t].y & 0xffff));
      pa.w += bf2f((unsigned short)(ec[t].y >> 16));
    }
  }
  *(float4*)&entpart[wave * 256 + lane * 4] = pa;
  __syncthreads();

  // rel gather (selected 32 rows) + combine ent partials
  float accR = 0.f;
#pragma unroll 2
  for (int k = 0; k < 32; k += 4) {
    const int n0 = list[k], n1 = list[k + 1], n2 = list[k + 2], n3 = list[k + 3];
    const float* p0 = emb + (size_t)rel_ids[n0] * 256;
    const float* p1 = emb + (size_t)rel_ids[n1] * 256;
    const float* p2 = emb + (size_t)rel_ids[n2] * 256;
    const float* p3 = emb + (size_t)rel_ids[n3] * 256;
    accR += (p0[tid] + p1[tid]) + (p2[tid] + p3[tid]);
  }
  const float accE = entpart[tid] + entpart[256 + tid] + entpart[512 + tid] +
                     entpart[768 + tid];
  mc[(size_t)r * 512 + tid] = f2bf(accR * (1.f / 32.f));
  mc[(size_t)r * 512 + 256 + tid] = f2bf(accE * (1.f / 32.f));
}

// ------------- bf16 MFMA GEMM_NT 128x128, global_load_lds staging ----------
// M % 128 == 0, N % 128 == 0, K % 32 == 0.
// modes: 0 normal (act/bias/addmat), 1 base+cell0, 2 step+cell.
__global__ __launch_bounds__(256) void gemm128_kernel(
    const unsigned short* __restrict__ A, int lda,
    const unsigned short* __restrict__ Bm, int ldb,
    float* __restrict__ C, unsigned short* __restrict__ Cbf,
    int M, int N, int K,
    const float* __restrict__ bias1, const float* __restrict__ bias2,
    const float* __restrict__ addmat, int act, int mode,
    float* __restrict__ cbuf, const float* __restrict__ qg,
    float* __restrict__ h, unsigned short* __restrict__ hbf) {
  __shared__ __align__(16) unsigned short As[128 * 32];
  __shared__ __align__(16) unsigned short Bs[128 * 32];
  const int tid = threadIdx.x;
  const int wid = tid >> 6, lane = tid & 63;
  const int quad = lane >> 4, l16 = lane & 15;
  const int wr = (wid >> 1) * 64, wc = (wid & 1) * 64;
  const int row0 = blockIdx.y * 128, col0 = blockIdx.x * 128;

  // staging: wave wid covers A rows [wid*32,+32) and B rows [wid*32,+32),
  // two 16-row global_load_lds(16) each. lane: row=lane>>2, physq=lane&3,
  // fetches logical quarter q = physq ^ ((lane>>3)&3)  (XOR swizzle).
  const int rl = lane >> 2;
  const int q = (lane & 3) ^ ((lane >> 3) & 3);
  const unsigned short* Ap0 = A + (size_t)(row0 + wid * 32 + rl) * lda + q * 8;
  const unsigned short* Ap1 = Ap0 + (size_t)16 * lda;
  const unsigned short* Bp0 = Bm + (size_t)(col0 + wid * 32 + rl) * ldb + q * 8;
  const unsigned short* Bp1 = Bp0 + (size_t)16 * ldb;
  unsigned short* lA0 = &As[(wid * 32) * 32];
  unsigned short* lA1 = &As[(wid * 32 + 16) * 32];
  unsigned short* lB0 = &Bs[(wid * 32) * 32];
  unsigned short* lB1 = &Bs[(wid * 32 + 16) * 32];

  // frag reads: row = wr/wc + i*16 + l16; physq = quad ^ ((l16>>1)&3)
  const int pq = quad ^ ((l16 >> 1) & 3);
  const unsigned short* fA = &As[(wr + l16) * 32 + pq * 8];
  const unsigned short* fB = &Bs[(wc + l16) * 32 + pq * 8];

  floatx4 acc[4][4];
#pragma unroll
  for (int i = 0; i < 4; ++i)
#pragma unroll
    for (int j = 0; j < 4; ++j) {
      floatx4 z = {0.f, 0.f, 0.f, 0.f};
      acc[i][j] = z;
    }

  for (int k0 = 0; k0 < K; k0 += 32) {
    load_lds16(Ap0, lA0);
    load_lds16(Ap1, lA1);
    load_lds16(Bp0, lB0);
    load_lds16(Bp1, lB1);
    Ap0 += 32; Ap1 += 32; Bp0 += 32; Bp1 += 32;
    __syncthreads();

    short8 af[4], bfr[4];
#pragma unroll
    for (int i = 0; i < 4; ++i) af[i] = *(const short8*)(fA + i * 16 * 32);
#pragma unroll
    for (int j = 0; j < 4; ++j) bfr[j] = *(const short8*)(fB + j * 16 * 32);
#pragma unroll
    for (int i = 0; i < 4; ++i)
#pragma unroll
      for (int j = 0; j < 4; ++j)
        acc[i][j] = __builtin_amdgcn_mfma_f32_16x16x32_bf16(af[i], bfr[j],
                                                            acc[i][j], 0, 0, 0);
    __syncthreads();
  }

#pragma unroll
  for (int i = 0; i < 4; ++i) {
#pragma unroll
    for (int r = 0; r < 4; ++r) {
      const int row = row0 + wr + i * 16 + quad * 4 + r;
      float vals[4];
#pragma unroll
      for (int j = 0; j < 4; ++j) {
        const int col = col0 + wc + j * 16 + l16;
        float v = acc[i][j][r];
        if (bias1) v += bias1[col];
        if (bias2) v += bias2[col];
        if (addmat) v += addmat[(size_t)row * N + col];
        vals[j] = v;
      }
      if (mode == 0) {
#pragma unroll
        for (int j = 0; j < 4; ++j) {
          const int col = col0 + wc + j * 16 + l16;
          float v = vals[j];
          if (act == 1) v = tanh_f(v);
          else if (act == 2) v = fmaxf(v, 0.f);
          if (C) C[(size_t)row * N + col] = v;
          if (Cbf) Cbf[(size_t)row * N + col] = f2bf(v);
        }
      } else {
        if (mode == 1) {
#pragma unroll
          for (int j = 0; j < 4; ++j)
            C[(size_t)row * N + (col0 + wc + j * 16 + l16)] = vals[j];
        }
        // j == gate (i,f,g,o) of gate-index n (weight-row permutation)
        const int n = (((col0 + wc) >> 6) << 4) + l16;
        const float cold = (mode == 1) ? 0.f : cbuf[(size_t)row * 1024 + n];
        const float cn =
            sigm_f(vals[1]) * cold + sigm_f(vals[0]) * tanh_f(vals[2]);
        cbuf[(size_t)row * 1024 + n] = cn;
        if (n < 512) {
          const float hv =
              qg[(size_t)row * 512 + n] + sigm_f(vals[3]) * tanh_f(cn);
          h[(size_t)row * 512 + n] = hv;
          hbf[(size_t)row * 512 + n] = f2bf(hv);
        }
      }
    }
  }
}

// ------------- bf16 MFMA GEMM_NT 64x64, global_load_lds staging ------------
// N % 64 == 0, K % 32 == 0, M arbitrary (A rows clamped; writes guarded).
// snptr != null => GCN remap epilogue (scatter rows to qn/qnb/sn).
__global__ __launch_bounds__(256) void gemm64_kernel(
    const unsigned short* __restrict__ A, int lda,
    const unsigned short* __restrict__ Bm, int ldb,
    float* __restrict__ C, unsigned short* __restrict__ Cbf,
    int M, int N, int K,
    const float* __restrict__ bias1, const float* __restrict__ bias2,
    const float* __restrict__ addmat, int act, int rB, int rF,
    float* __restrict__ snptr) {
  __shared__ __align__(16) unsigned short As[64 * 32];
  __shared__ __align__(16) unsigned short Bs[64 * 32];
  const int tid = threadIdx.x;
  const int wid = tid >> 6, lane = tid & 63;
  const int quad = lane >> 4, l16 = lane & 15;
  const int wr = (wid >> 1) * 32, wc = (wid & 1) * 32;
  const int row0 = blockIdx.y * 64, col0 = blockIdx.x * 64;

  // staging: waves 0,1 -> A rows [0,32)/[32,64); waves 2,3 -> B likewise
  const int half = wid >> 1;       // 0=A 1=B
  const int grp = (wid & 1) * 32;
  const int rl = lane >> 2;
  const int q = (lane & 3) ^ ((lane >> 3) & 3);
  const unsigned short* src = half ? Bm : A;
  const int lds = half ? ldb : lda;
  const int r0s = half ? col0 : row0;
  int rg0 = r0s + grp + rl;
  int rg1 = rg0 + 16;
  if (!half) {  // clamp A rows (data valid; epilogue guards writes)
    rg0 = min(rg0, M - 1);
    rg1 = min(rg1, M - 1);
  }
  const unsigned short* P0 = src + (size_t)rg0 * lds + q * 8;
  const unsigned short* P1 = src + (size_t)rg1 * lds + q * 8;
  unsigned short* L0 = (half ? Bs : As) + grp * 32;
  unsigned short* L1 = L0 + 16 * 32;

  const int pq = quad ^ ((l16 >> 1) & 3);
  const unsigned short* fA = &As[(wr + l16) * 32 + pq * 8];
  const unsigned short* fB = &Bs[(wc + l16) * 32 + pq * 8];

  floatx4 acc[2][2];
#pragma unroll
  for (int i = 0; i < 2; ++i)
#pragma unroll
    for (int j = 0; j < 2; ++j) {
      floatx4 z = {0.f, 0.f, 0.f, 0.f};
      acc[i][j] = z;
    }

  for (int k0 = 0; k0 < K; k0 += 32) {
    load_lds16(P0, L0);
    load_lds16(P1, L1);
    P0 += 32; P1 += 32;
    __syncthreads();

    short8 af[2], bfr[2];
#pragma unroll
    for (int i = 0; i < 2; ++i) af[i] = *(const short8*)(fA + i * 16 * 32);
#pragma unroll
    for (int j = 0; j < 2; ++j) bfr[j] = *(const short8*)(fB + j * 16 * 32);
#pragma unroll
    for (int i = 0; i < 2; ++i)
#pragma unroll
      for (int j = 0; j < 2; ++j)
        acc[i][j] = __builtin_amdgcn_mfma_f32_16x16x32_bf16(af[i], bfr[j],
                                                            acc[i][j], 0, 0, 0);
    __syncthreads();
  }

#pragma unroll
  for (int i = 0; i < 2; ++i) {
#pragma unroll
    for (int r = 0; r < 4; ++r) {
      const int row = row0 + wr + i * 16 + quad * 4 + r;
      if (row >= M) continue;
#pragma unroll
      for (int j = 0; j < 2; ++j) {
        const int col = col0 + wc + j * 16 + l16;
        float v = acc[i][j][r];
        if (bias1) v += bias1[col];
        if (bias2) v += bias2[col];
        if (addmat) v += addmat[(size_t)row * N + col];
        if (act == 1) v = tanh_f(v);
        else if (act == 2) v = fmaxf(v, 0.f);
        if (snptr) {  // GCN remap: row -> {qn | qn+256 | sn | sn+256}
          if (row < rB) {
            C[(size_t)row * 512 + col] = v;
            Cbf[(size_t)row * 512 + col] = f2bf(v);
          } else if (row < 2 * rB) {
            C[(size_t)(row - rB) * 512 + 256 + col] = v;
            Cbf[(size_t)(row - rB) * 512 + 256 + col] = f2bf(v);
          } else if (row < 2 * rB + rF) {
            snptr[(size_t)(row - 2 * rB) * 512 + col] = v;
          } else {
            snptr[(size_t)(row - 2 * rB - rF) * 512 + 256 + col] = v;
          }
        } else {
          if (C) C[(size_t)row * N + col] = v;
          if (Cbf) Cbf[(size_t)row * N + col] = f2bf(v);
        }
      }
    }
  }
}

// ------------- fp32 GEMM_NT (tiny M=F support path) ------------------------
__global__ __launch_bounds__(256) void gemm_nt_kernel(
    const float* __restrict__ A, int lda, const float* __restrict__ B, int ldb,
    float* __restrict__ C, int M, int N, int K,
    const float* __restrict__ bias1, const float* __restrict__ bias2,
    const float* __restrict__ addmat, int act) {
  __shared__ float As[16][65];
  __shared__ float Bs[16][65];
  const int tid = threadIdx.x;
  const int col0 = blockIdx.x * 64;
  const int row0 = blockIdx.y * 64;
  const int tx = tid & 15, ty = tid >> 4;
  const int lr = tid >> 2, lk = (tid & 3) << 2;

  float acc[4][4];
#pragma unroll
  for (int i = 0; i < 4; ++i)
#pragma unroll
    for (int j = 0; j < 4; ++j) acc[i][j] = 0.f;

  const int ar = row0 + lr;
  const bool avalid = ar < M;
  const float* Aptr = A + (size_t)ar * lda + lk;
  const float* Bptr = B + (size_t)(col0 + lr) * ldb + lk;

  for (int k0 = 0; k0 < K; k0 += 16) {
    float4 av = make_float4(0.f, 0.f, 0.f, 0.f);
    if (avalid) av = *(const float4*)(Aptr + k0);
    float4 bv = *(const float4*)(Bptr + k0);
    As[lk + 0][lr] = av.x; As[lk + 1][lr] = av.y;
    As[lk + 2][lr] = av.z; As[lk + 3][lr] = av.w;
    Bs[lk + 0][lr] = bv.x; Bs[lk + 1][lr] = bv.y;
    Bs[lk + 2][lr] = bv.z; Bs[lk + 3][lr] = bv.w;
    __syncthreads();
#pragma unroll
    for (int k = 0; k < 16; ++k) {
      float a0 = As[k][ty * 4 + 0], a1 = As[k][ty * 4 + 1];
      float a2 = As[k][ty * 4 + 2], a3 = As[k][ty * 4 + 3];
      float b0 = Bs[k][tx * 4 + 0], b1 = Bs[k][tx * 4 + 1];
      float b2 = Bs[k][tx * 4 + 2], b3 = Bs[k][tx * 4 + 3];
      acc[0][0] += a0 * b0; acc[0][1] += a0 * b1; acc[0][2] += a0 * b2; acc[0][3] += a0 * b3;
      acc[1][0] += a1 * b0; acc[1][1] += a1 * b1; acc[1][2] += a1 * b2; acc[1][3] += a1 * b3;
      acc[2][0] += a2 * b0; acc[2][1] += a2 * b1; acc[2][2] += a2 * b2; acc[2][3] += a2 * b3;
      acc[3][0] += a3 * b0; acc[3][1] += a3 * b1; acc[3][2] += a3 * b2; acc[3][3] += a3 * b3;
    }
    __syncthreads();
  }

#pragma unroll
  for (int i = 0; i < 4; ++i) {
    const int r = row0 + ty * 4 + i;
    if (r >= M) continue;
#pragma unroll
    for (int j = 0; j < 4; ++j) {
      const int c = col0 + tx * 4 + j;
      float v = acc[i][j];
      if (bias1) v += bias1[c];
      if (bias2) v += bias2[c];
      if (addmat) v += addmat[(size_t)r * N + c];
      if (act == 1) v = tanhf(v);
      else if (act == 2) v = fmaxf(v, 0.f);
      C[(size_t)r * N + c] = v;
    }
  }
}

// ------------- LayerNorm rows of 512; optional bf16 copy (queries) ---------
__global__ __launch_bounds__(256) void ln_kernel(
    const float* __restrict__ X, float* __restrict__ Y,
    unsigned short* __restrict__ Ybf,
    const float* __restrict__ g, const float* __restrict__ bta) {
  const int r = blockIdx.x;
  const int tid = threadIdx.x;
  const float* x = X + (size_t)r * 512;
  float x0 = x[tid], x1 = x[tid + 256];
  __shared__ float red[4];
  float s = wave_reduce_sum(x0 + x1);
  if ((tid & 63) == 0) red[tid >> 6] = s;
  __syncthreads();
  const float mean = (red[0] + red[1] + red[2] + red[3]) * (1.f / 512.f);
  __syncthreads();
  const float d0 = x0 - mean, d1 = x1 - mean;
  float v = wave_reduce_sum(d0 * d0 + d1 * d1);
  if ((tid & 63) == 0) red[tid >> 6] = v;
  __syncthreads();
  const float var = (red[0] + red[1] + red[2] + red[3]) * (1.f / 512.f);
  const float inv = 1.f / sqrtf(var + 1e-5f);
  const float y0 = d0 * inv * g[tid] + bta[tid];
  const float y1 = d1 * inv * g[tid + 256] + bta[tid + 256];
  float* y = Y + (size_t)r * 512;
  y[tid] = y0;
  y[tid + 256] = y1;
  if (Ybf) {
    Ybf[(size_t)r * 512 + tid] = f2bf(y0);
    Ybf[(size_t)r * 512 + tid + 256] = f2bf(y1);
  }
}

// ------------- support LN (F rows) + mean -> sg, single block --------------
__global__ __launch_bounds__(256) void lns_kernel(
    const float* __restrict__ X, const float* __restrict__ g,
    const float* __restrict__ bta, float* __restrict__ sg, int F) {
  const int tid = threadIdx.x;
  __shared__ float red[4];
  float a0 = 0.f, a1 = 0.f;
  for (int f = 0; f < F; ++f) {
    const float* x = X + (size_t)f * 512;
    const float x0 = x[tid], x1 = x[tid + 256];
    float s = wave_reduce_sum(x0 + x1);
    if ((tid & 63) == 0) red[tid >> 6] = s;
    __syncthreads();
    const float mean = (red[0] + red[1] + red[2] + red[3]) * (1.f / 512.f);
    __syncthreads();
    const float d0 = x0 - mean, d1 = x1 - mean;
    float v = wave_reduce_sum(d0 * d0 + d1 * d1);
    if ((tid & 63) == 0) red[tid >> 6] = v;
    __syncthreads();
    const float var = (red[0] + red[1] + red[2] + red[3]) * (1.f / 512.f);
    const float inv = 1.f / sqrtf(var + 1e-5f);
    a0 += d0 * inv * g[tid] + bta[tid];
    a1 += d1 * inv * g[tid + 256] + bta[tid + 256];
    __syncthreads();
  }
  sg[tid] = a0 / (float)F;
  sg[tid + 256] = a1 / (float)F;
}

// ------------- cvec[jp] = sum_d sg[d] * w_hh[orig(jp), 512+d] (permuted) ---
__global__ __launch_bounds__(256) void cvec_kernel(
    const float* __restrict__ whh, const float* __restrict__ sg,
    float* __restrict__ cv) {
  const int wave = threadIdx.x >> 6, lane = threadIdx.x & 63;
  const int jp = blockIdx.x * 4 + wave;
  const int orig = ((jp >> 4) & 3) * 1024 + ((jp >> 6) << 4) + (jp & 15);
  const float* wr = whh + (size_t)orig * 1024 + 512;
  float s = 0.f;
#pragma unroll
  for (int d = lane; d < 512; d += 64) s += wr[d] * sg[d];
  s = wave_reduce_sum(s);
  if (lane == 0) cv[jp] = s;
}

// ------------- out[b] = cosine(h[b], sg) -----------------------------------
__global__ __launch_bounds__(256) void final_kernel(
    const float* __restrict__ h, const float* __restrict__ sg,
    float* __restrict__ out) {
  const int b = blockIdx.x, tid = threadIdx.x;
  const float* hr = h + (size_t)b * 512;
  const float h0 = hr[tid], h1 = hr[tid + 256];
  const float s0 = sg[tid], s1 = sg[tid + 256];
  float d = h0 * s0 + h1 * s1;
  float hh = h0 * h0 + h1 * h1;
  float ssq = s0 * s0 + s1 * s1;
  __shared__ float red[3][4];
  d = wave_reduce_sum(d);
  hh = wave_reduce_sum(hh);
  ssq = wave_reduce_sum(ssq);
  if ((tid & 63) == 0) {
    red[0][tid >> 6] = d; red[1][tid >> 6] = hh; red[2][tid >> 6] = ssq;
  }
  __syncthreads();
  if (tid == 0) {
    const float D = red[0][0] + red[0][1] + red[0][2] + red[0][3];
    const float H = red[1][0] + red[1][1] + red[1][2] + red[1][3];
    const float S = red[2][0] + red[2][1] + red[2][2] + red[2][3];
    out[b] = D / (fmaxf(sqrtf(H), 1e-12f) * fmaxf(sqrtf(S), 1e-12f));
  }
}

extern "C" void kernel_launch(void* const* d_in, const int* in_sizes, int n_in,
                              void* d_out, int out_size, void* d_ws, size_t ws_size,
                              hipStream_t stream) {
  const int* query = (const int*)d_in[0];
  const int* support = (const int*)d_in[1];
  const int* qlc = (const int*)d_in[2];
  const int* qrc = (const int*)d_in[4];
  const int* slc = (const int*)d_in[6];
  const int* src_ = (const int*)d_in[8];
  const float* emb = (const float*)d_in[10];
  const float* gcn_w = (const float*)d_in[11];
  const float* gcn_wb = (const float*)d_in[12];
  const float* gcn_b = (const float*)d_in[13];
  const float* p1_w = (const float*)d_in[14];
  const float* p1_b = (const float*)d_in[15];
  const float* p2_w = (const float*)d_in[16];
  const float* p2_b = (const float*)d_in[17];
  const float* ln_g = (const float*)d_in[18];
  const float* ln_b = (const float*)d_in[19];
  const float* w_ih = (const float*)d_in[20];
  const float* w_hh = (const float*)d_in[21];
  const float* b_ih = (const float*)d_in[22];
  const float* b_hh = (const float*)d_in[23];
  float* out = (float*)d_out;

  const int B = in_sizes[0] / 2;   // 2048
  const int F = in_sizes[1] / 2;   // 5
  const int NR = 2 * B + 2 * F;    // 4106

  char* Wb = (char*)d_ws;
  size_t off = 0;
  auto alloc = [&](size_t bytes) {
    size_t o = off;
    off += (bytes + 255) & ~(size_t)255;
    return o;
  };
  const size_t base_o = alloc((size_t)B * 4096 * 4);
  const size_t mc_o   = alloc((size_t)NR * 512 * 2);
  const size_t qn_o   = alloc((size_t)B * 512 * 4);
  const size_t qnb_o  = alloc((size_t)B * 512 * 2);
  const size_t hqb_o  = alloc((size_t)B * 1024 * 2);
  const size_t oq_o   = alloc((size_t)B * 512 * 4);
  const size_t qg_o   = alloc((size_t)B * 512 * 4);
  const size_t qgb_o  = alloc((size_t)B * 512 * 2);
  const size_t cbuf_o = alloc((size_t)B * 1024 * 4);
  const size_t h_o    = alloc((size_t)B * 512 * 4);
  const size_t hb0_o  = alloc((size_t)B * 512 * 2);
  const size_t hb1_o  = alloc((size_t)B * 512 * 2);
  const size_t wihb_o = alloc((size_t)4096 * 512 * 2);
  const size_t whhb_o = alloc((size_t)4096 * 512 * 2);
  const size_t p1b_o  = alloc((size_t)1024 * 512 * 2);
  const size_t p2b_o  = alloc((size_t)512 * 1024 * 2);
  const size_t gcnb_o = alloc((size_t)256 * 512 * 2);
  const size_t bcomb_o= alloc(4096 * 4);
  const size_t sn_o   = alloc((size_t)F * 512 * 4);
  const size_t hs_o   = alloc((size_t)F * 1024 * 4);
  const size_t oss_o  = alloc((size_t)F * 512 * 4);
  const size_t sg_o   = alloc(512 * 4);
  const size_t cvec_o = alloc(4096 * 4);

  auto F32 = [&](size_t o) { return (float*)(Wb + o); };
  auto BF = [&](size_t o) { return (unsigned short*)(Wb + o); };

  // 0. weight converts + gate permutation + combined bias
  convert_all_kernel<<<5252, 256, 0, stream>>>(
      w_ih, w_hh, p1_w, p2_w, gcn_w, b_ih, b_hh, BF(wihb_o), BF(whhb_o),
      BF(p1b_o), BF(p2b_o), BF(gcnb_o), F32(bcomb_o));

  // 1. neighbor encoder -> mc (NR x 512, bf16)
  neighbor_kernel<<<NR, 256, 0, stream>>>(query, support, qlc, qrc, slc, src_,
                                          emb, BF(mc_o), B, F);
  // 2. GCN + remap fused
  {
    dim3 g(256 / 64, (NR + 63) / 64);
    gemm64_kernel<<<g, 256, 0, stream>>>(BF(mc_o), 512, BF(gcnb_o), 512,
                                         F32(qn_o), BF(qnb_o), NR, 256, 512,
                                         gcn_wb, gcn_b, nullptr, 1, B, F,
                                         F32(sn_o));
  }
  // 3-4. support_encoder(queries)
  {
    dim3 g(1024 / 64, B / 64);
    gemm64_kernel<<<g, 256, 0, stream>>>(BF(qnb_o), 512, BF(p1b_o), 512,
                                         nullptr, BF(hqb_o), B, 1024, 512,
                                         p1_b, nullptr, nullptr, 2, 0, 0,
                                         nullptr);
  }
  {
    dim3 g(512 / 64, B / 64);
    gemm64_kernel<<<g, 256, 0, stream>>>(BF(hqb_o), 1024, BF(p2b_o), 1024,
                                         F32(oq_o), nullptr, B, 512, 1024,
                                         p2_b, nullptr, F32(qn_o), 0, 0, 0,
                                         nullptr);
  }
  // 5-6. support_encoder(supports): fp32 (M=5)
  {
    dim3 g(1024 / 64, 1);
    gemm_nt_kernel<<<g, 256, 0, stream>>>(F32(sn_o), 512, p1_w, 512, F32(hs_o),
                                          F, 1024, 512, p1_b, nullptr, nullptr,
                                          2);
  }
  {
    dim3 g(512 / 64, 1);
    gemm_nt_kernel<<<g, 256, 0, stream>>>(F32(hs_o), 1024, p2_w, 1024,
                                          F32(oss_o), F, 512, 1024, p2_b,
                                          nullptr, F32(sn_o), 0);
  }
  // 7. support LN + mean -> sg (one block)
  lns_kernel<<<1, 256, 0, stream>>>(F32(oss_o), ln_g, ln_b, F32(sg_o), F);
  // 8. LN queries -> qg f32 + bf16
  ln_kernel<<<B, 256, 0, stream>>>(F32(oq_o), F32(qg_o), BF(qgb_o), ln_g, ln_b);
  // 9. cvec (gate-permuted)
  cvec_kernel<<<1024, 256, 0, stream>>>(w_hh, F32(sg_o), F32(cvec_o));
  // 10. base GEMM + fused cell step 0
  {
    dim3 g(4096 / 128, B / 128);
    gemm128_kernel<<<g, 256, 0, stream>>>(
        BF(qgb_o), 512, BF(wihb_o), 512, F32(base_o), nullptr, B, 4096, 512,
        F32(bcomb_o), nullptr, nullptr, 0, 1, F32(cbuf_o), F32(qg_o), F32(h_o),
        BF(hb0_o));
  }
  // 11-13. steps 1..3 (hb double-buffered)
  for (int s = 1; s < 4; ++s) {
    const size_t in_o = (s & 1) ? hb0_o : hb1_o;
    const size_t out_o = (s & 1) ? hb1_o : hb0_o;
    dim3 g(4096 / 128, B / 128);
    gemm128_kernel<<<g, 256, 0, stream>>>(
        BF(in_o), 512, BF(whhb_o), 512, nullptr, nullptr, B, 4096, 512,
        F32(cvec_o), nullptr, F32(base_o), 0, 2, F32(cbuf_o), F32(qg_o),
        F32(h_o), BF(out_o));
  }
  // 14. output
  final_kernel<<<B, 256, 0, stream>>>(F32(h_o), F32(sg_o), out);
}